// Round 3
// baseline (880.399 us; speedup 1.0000x reference)
//
#include <hip/hip_runtime.h>
#include <math.h>

#define NB 4
#define SEQ 8192
#define NT (NB*SEQ)        // 32768 tokens
#define HDIM 64
#define NST 16
#define NBLK 4
#define KCONV 16
#define DIN 128
#define PDIM 16            // head dim
#define NH 8
#define CDIM 160
#define EPROJ 296
#define CH 128             // chunk length
#define NC 64              // chunks per sequence

__device__ __forceinline__ float sigf(float x){ return 1.0f/(1.0f+__expf(-x)); }

// h[t][d] = x[t] * w_in[d]
__global__ __launch_bounds__(256) void k_init_h(const float* __restrict__ x, const float* __restrict__ w_in,
                                                float* __restrict__ h){
  int i = blockIdx.x*256 + threadIdx.x;
  int t = i >> 6, d = i & 63;
  h[i] = x[t]*w_in[d];
}

// zx[e][t] = sum_d h[t][d] * w[e][d]   (channel-major output)
// 16 tokens/block, d-dim split across lane pairs (shfl_xor 16 combine):
// VGPR ~60 -> 8 waves/SIMD; grid 2048 = 8 blocks/CU.
__global__ __launch_bounds__(256) void k_inproj(const float* __restrict__ h, const float* __restrict__ w,
                                                float* __restrict__ zx){
  int tid = threadIdx.x;
  int tok = blockIdx.x*16 + (tid & 15);
  int dg  = (tid >> 4) & 1;
  int eg  = tid >> 5;            // 0..7
  float4 hr[8];
  const float4* hp = (const float4*)(h + (size_t)tok*HDIM) + dg*8;
#pragma unroll
  for(int i=0;i<8;i++) hr[i] = hp[i];
  for(int e = eg; e < EPROJ; e += 8){
    const float4* wr = (const float4*)(w + (size_t)e*HDIM) + dg*8;
    float acc = 0.f;
#pragma unroll
    for(int i=0;i<8;i++){
      float4 wv = wr[i];
      acc += hr[i].x*wv.x + hr[i].y*wv.y + hr[i].z*wv.z + hr[i].w*wv.w;
    }
    acc += __shfl_xor(acc, 16);
    if(dg == 0) zx[(size_t)e*NT + tok] = acc;
  }
}

// depthwise causal conv over l (16 taps) + bias + silu; input = zx channels [DIN, DIN+CDIM)
__global__ __launch_bounds__(256) void k_conv(const float* __restrict__ zx, const float* __restrict__ cw,
                                              const float* __restrict__ cb, float* __restrict__ xbc){
  int c = blockIdx.x >> 7;          // NT/256 = 128 tiles
  int t = (blockIdx.x & 127)*256 + threadIdx.x;
  int l = t & (SEQ-1);
  const float* in = zx + (size_t)(DIN + c)*NT;
  float acc = cb[c];
#pragma unroll
  for(int k=0;k<KCONV;k++){
    int ll = l - (KCONV-1) + k;
    float v = (ll >= 0) ? in[t - (KCONV-1) + k] : 0.f;
    acc += cw[c*KCONV + k] * v;
  }
  xbc[(size_t)c*NT + t] = acc * sigf(acc);
}

// dt[hh][t] = softplus(zx[288+hh][t] + dt_bias[hh])
__global__ __launch_bounds__(256) void k_dt(const float* __restrict__ zx, const float* __restrict__ dtb,
                                            float* __restrict__ dt){
  int hh = blockIdx.x >> 7;
  int t = (blockIdx.x & 127)*256 + threadIdx.x;
  float raw = zx[(size_t)(DIN + CDIM + hh)*NT + t] + dtb[hh];
  dt[(size_t)hh*NT + t] = (raw > 20.f) ? raw : log1pf(__expf(raw));
}

// per-(b,chunk,head): inclusive cumsum of dA = dt*A within chunk; store acs + chunk total asum
__global__ __launch_bounds__(64) void k_cumsum(const float* __restrict__ dt, const float* __restrict__ alog,
                                               float* __restrict__ acs, float* __restrict__ asum){
  int hh = blockIdx.x & 7;
  int c  = (blockIdx.x >> 3) & 63;
  int b  = blockIdx.x >> 9;
  int lane = threadIdx.x;
  int t0 = b*SEQ + c*CH;
  float A = -__expf(alog[hh]);
  float2 d2 = *(const float2*)(dt + (size_t)hh*NT + t0 + 2*lane);
  float v0 = d2.x*A, v1 = d2.y*A;
  float s = v0 + v1;
  for(int off=1; off<64; off<<=1){
    float o = __shfl_up(s, off);
    if(lane >= off) s += o;
  }
  float excl = s - (v0+v1);
  *(float2*)(acs + (size_t)hh*NT + t0 + 2*lane) = make_float2(excl+v0, excl+v0+v1);
  if(lane == 63) asum[(b*NC + c)*NH + hh] = s;
}

// chunk states S[b,c,h,p,n] = sum_s B[s,n] * xs[s,h,p] * dt[s] * exp(asum - acs[s])
__global__ __launch_bounds__(256) void k_states(const float* __restrict__ xbc, const float* __restrict__ dt,
                                                const float* __restrict__ acs, const float* __restrict__ asum,
                                                float* __restrict__ S){
  int hh = blockIdx.x & 7;
  int c  = (blockIdx.x >> 3) & 63;
  int b  = blockIdx.x >> 9;
  int t0 = b*SEQ + c*CH;
  __shared__ float Bl[CH][NST+4];
  __shared__ float Xl[CH][PDIM+4];
  __shared__ float Wl[CH];
  int tid = threadIdx.x;
#pragma unroll
  for(int r=0;r<8;r++){
    int idx = tid + r*256;
    int s = idx & 127, n = idx >> 7;
    Bl[s][n] = xbc[(size_t)(DIN + n)*NT + t0 + s];
    Xl[s][n] = xbc[(size_t)(hh*PDIM + n)*NT + t0 + s];
  }
  if(tid < 128){
    float as = asum[(b*NC + c)*NH + hh];
    Wl[tid] = dt[(size_t)hh*NT + t0 + tid] * __expf(as - acs[(size_t)hh*NT + t0 + tid]);
  }
  __syncthreads();
  int n = tid & 15, p = tid >> 4;
  float acc = 0.f;
#pragma unroll 4
  for(int s=0;s<CH;s++) acc += Bl[s][n] * (Xl[s][p] * Wl[s]);
  S[((size_t)(b*NC + c)*NH + hh)*256 + tid] = acc;
}

// sequential scan over 64 chunks: prev[c] = state entering chunk c
// 128 blocks x 64 threads (element dim split 4-ways) + S prefetch.
__global__ __launch_bounds__(64) void k_scan(const float* __restrict__ S, const float* __restrict__ asum,
                                             const float* __restrict__ init, float* __restrict__ prev){
  int q  = blockIdx.x & 3;
  int hh = (blockIdx.x >> 2) & 7;
  int b  = blockIdx.x >> 5;
  int el = q*64 + threadIdx.x;
  float r = init[hh*256 + el];
  float Sc = S[((size_t)(b*NC)*NH + hh)*256 + el];
  for(int c=0;c<NC;c++){
    size_t base = ((size_t)(b*NC + c)*NH + hh)*256 + el;
    float Sn = (c+1 < NC) ? S[base + NH*256] : 0.f;
    prev[base] = r;
    r = __expf(asum[(b*NC + c)*NH + hh])*r + Sc;
    Sc = Sn;
  }
}

// per-(b,chunk,head): Y = (tril(C B^T * decay * dt) X + C prev^T exp(acs) + D*xs) * silu(z)
__global__ __launch_bounds__(128) void k_y(const float* __restrict__ xbc, const float* __restrict__ zx,
                                           const float* __restrict__ dt, const float* __restrict__ acs,
                                           const float* __restrict__ prev, const float* __restrict__ dskip,
                                           float* __restrict__ y){
  int hh = blockIdx.x & 7;
  int c  = (blockIdx.x >> 3) & 63;
  int b  = blockIdx.x >> 9;
  int t0 = b*SEQ + c*CH;
  __shared__ __align__(16) float Bl[CH][NST+4];
  __shared__ __align__(16) float Xl[CH][PDIM+4];
  __shared__ float Al[CH];
  __shared__ float Dtl[CH];
  __shared__ float Pl[256];
  int tid = threadIdx.x;
#pragma unroll
  for(int r=0;r<16;r++){
    Bl[tid][r] = xbc[(size_t)(DIN + r)*NT + t0 + tid];
    Xl[tid][r] = xbc[(size_t)(hh*PDIM + r)*NT + t0 + tid];
  }
  Al[tid]  = acs[(size_t)hh*NT + t0 + tid];
  Dtl[tid] = dt[(size_t)hh*NT + t0 + tid];
  {
    size_t pb = ((size_t)(b*NC + c)*NH + hh)*256;
    Pl[tid]     = prev[pb + tid];
    Pl[tid+128] = prev[pb + tid + 128];
  }
  __syncthreads();
  int l = tid;
  float C[16];
#pragma unroll
  for(int n=0;n<16;n++) C[n] = xbc[(size_t)(DIN+NST+n)*NT + t0 + l];
  float a_l = Al[l];
  float acc[16];
#pragma unroll
  for(int p=0;p<16;p++) acc[p]=0.f;
  for(int s=0;s<=l;s++){
    const float4* bp = (const float4*)&Bl[s][0];
    float4 b0=bp[0], b1=bp[1], b2=bp[2], b3=bp[3];
    float dots = C[0]*b0.x + C[1]*b0.y + C[2]*b0.z + C[3]*b0.w
               + C[4]*b1.x + C[5]*b1.y + C[6]*b1.z + C[7]*b1.w
               + C[8]*b2.x + C[9]*b2.y + C[10]*b2.z + C[11]*b2.w
               + C[12]*b3.x + C[13]*b3.y + C[14]*b3.z + C[15]*b3.w;
    float w = dots * __expf(a_l - Al[s]) * Dtl[s];
    const float4* xp = (const float4*)&Xl[s][0];
    float4 x0=xp[0], x1=xp[1], x2=xp[2], x3=xp[3];
    acc[0] +=w*x0.x; acc[1] +=w*x0.y; acc[2] +=w*x0.z; acc[3] +=w*x0.w;
    acc[4] +=w*x1.x; acc[5] +=w*x1.y; acc[6] +=w*x1.z; acc[7] +=w*x1.w;
    acc[8] +=w*x2.x; acc[9] +=w*x2.y; acc[10]+=w*x2.z; acc[11]+=w*x2.w;
    acc[12]+=w*x3.x; acc[13]+=w*x3.y; acc[14]+=w*x3.z; acc[15]+=w*x3.w;
  }
  float ea = __expf(a_l);
#pragma unroll
  for(int p=0;p<16;p++){
    float ts = 0.f;
#pragma unroll
    for(int n=0;n<16;n++) ts += C[n]*Pl[p*16+n];
    acc[p] += ea*ts;
  }
  float Dk = dskip[hh];
#pragma unroll
  for(int p=0;p<16;p++){
    float zv = zx[(size_t)(hh*PDIM + p)*NT + t0 + l];
    float g = zv * sigf(zv);
    acc[p] = (acc[p] + Dk*Xl[l][p]) * g;
  }
  float4* yo = (float4*)(y + (size_t)(t0+l)*DIN + hh*PDIM);
  yo[0] = make_float4(acc[0], acc[1], acc[2], acc[3]);
  yo[1] = make_float4(acc[4], acc[5], acc[6], acc[7]);
  yo[2] = make_float4(acc[8], acc[9], acc[10],acc[11]);
  yo[3] = make_float4(acc[12],acc[13],acc[14],acc[15]);
}

// RMSNorm(y) -> out_proj(64x128) -> softsign -> mlp(64x64)+bias -> h +=
__global__ __launch_bounds__(256) void k_out(const float* __restrict__ y, const float* __restrict__ nw,
                                             const float* __restrict__ opw, const float* __restrict__ mw,
                                             const float* __restrict__ mb, float* __restrict__ h){
  __shared__ float ss[32];
  __shared__ float nwl[128];
  __shared__ float mbl[64];
  __shared__ __align__(16) float yt[32][132];
  __shared__ __align__(16) float W[64][132];
  int tid = threadIdx.x;
  int t0 = blockIdx.x * 32;
  int ln = tid & 63;

  if(tid < 128) nwl[tid] = nw[tid];
  else if(tid < 192) mbl[tid-128] = mb[tid-128];

  const float4* yg = (const float4*)(y + (size_t)t0*DIN);
#pragma unroll
  for(int k=0;k<4;k++){
    int fi = tid + k*256;
    float4 f = yg[fi];
    int tok = fi >> 5, c4 = fi & 31;
    *(float4*)&yt[tok][c4*4] = f;
    float d = f.x*f.x + f.y*f.y + f.z*f.z + f.w*f.w;
    d += __shfl_xor(d, 1); d += __shfl_xor(d, 2); d += __shfl_xor(d, 4);
    d += __shfl_xor(d, 8); d += __shfl_xor(d, 16);
    if((ln & 31) == 0) ss[tok] = d;
  }
  const float4* wg = (const float4*)opw;
#pragma unroll
  for(int k=0;k<8;k++){
    int fi = tid + k*256;
    int r = fi >> 5, c4 = fi & 31;
    *(float4*)&W[r][c4*4] = wg[fi];
  }
  __syncthreads();

#pragma unroll
  for(int k=0;k<4;k++){
    int fi = tid + k*256;
    int tok = fi >> 5, c4 = fi & 31;
    float r = rsqrtf(ss[tok]*(1.0f/128.0f) + 1e-5f);
    float4 v = *(float4*)&yt[tok][c4*4];
    float4 wv = ((const float4*)nwl)[c4];
    v.x *= r*wv.x; v.y *= r*wv.y; v.z *= r*wv.z; v.w *= r*wv.w;
    *(float4*)&yt[tok][c4*4] = v;
  }
  __syncthreads();

  int to = tid & 15, tk = tid >> 4;
  float acc0[4] = {0,0,0,0}, acc1[4] = {0,0,0,0};
#pragma unroll
  for(int n4=0;n4<32;n4++){
    float4 x0 = *(const float4*)&yt[2*tk][n4*4];
    float4 x1 = *(const float4*)&yt[2*tk+1][n4*4];
#pragma unroll
    for(int j=0;j<4;j++){
      float4 wv = *(const float4*)&W[to + 16*j][n4*4];
      acc0[j] += x0.x*wv.x + x0.y*wv.y + x0.z*wv.z + x0.w*wv.w;
      acc1[j] += x1.x*wv.x + x1.y*wv.y + x1.z*wv.z + x1.w*wv.w;
    }
  }
  __syncthreads();

  float* Wf = &W[0][0];
  float* tb = Wf + 4352;
#pragma unroll
  for(int j=0;j<4;j++){
    float o0 = acc0[j], o1 = acc1[j];
    tb[(2*tk)*68   + to + 16*j] = o0*rsqrtf(1.0f + o0*o0);
    tb[(2*tk+1)*68 + to + 16*j] = o1*rsqrtf(1.0f + o1*o1);
  }
  const float4* mg = (const float4*)mw;
#pragma unroll
  for(int k=0;k<4;k++){
    int fi = tid + k*256;
    int r = fi >> 4, c4 = fi & 15;
    *(float4*)&Wf[r*68 + c4*4] = mg[fi];
  }
  __syncthreads();

  float a20[4] = {0,0,0,0}, a21[4] = {0,0,0,0};
#pragma unroll
  for(int n4=0;n4<16;n4++){
    float4 x0 = *(const float4*)&tb[(2*tk)*68   + n4*4];
    float4 x1 = *(const float4*)&tb[(2*tk+1)*68 + n4*4];
#pragma unroll
    for(int j=0;j<4;j++){
      float4 wv = *(const float4*)&Wf[(to + 16*j)*68 + n4*4];
      a20[j] += x0.x*wv.x + x0.y*wv.y + x0.z*wv.z + x0.w*wv.w;
      a21[j] += x1.x*wv.x + x1.y*wv.y + x1.z*wv.z + x1.w*wv.w;
    }
  }
#pragma unroll
  for(int j=0;j<4;j++){
    int d = to + 16*j;
    float bias = mbl[d];
    h[(size_t)(t0 + 2*tk)*HDIM + d]     += a20[j] + bias;
    h[(size_t)(t0 + 2*tk + 1)*HDIM + d] += a21[j] + bias;
  }
}

__global__ __launch_bounds__(256) void k_final(const float* __restrict__ h, const float* __restrict__ wout,
                                               float* __restrict__ out){
  int t = blockIdx.x*256 + threadIdx.x;
  const float4* hp = (const float4*)(h + (size_t)t*HDIM);
  float acc = 0.f;
#pragma unroll
  for(int i=0;i<16;i++){
    float4 hv = hp[i]; float4 wv = ((const float4*)wout)[i];
    acc += hv.x*wv.x + hv.y*wv.y + hv.z*wv.z + hv.w*wv.w;
  }
  out[t] = acc;
}

extern "C" void kernel_launch(void* const* d_in, const int* in_sizes, int n_in,
                              void* d_out, int out_size, void* d_ws, size_t ws_size,
                              hipStream_t stream){
  const float* x          = (const float*)d_in[0];
  const float* w_in       = (const float*)d_in[1];
  const float* w_out      = (const float*)d_in[2];
  const float* in_proj_w  = (const float*)d_in[3];
  const float* conv_w     = (const float*)d_in[4];
  const float* conv_b     = (const float*)d_in[5];
  const float* dt_bias    = (const float*)d_in[6];
  const float* A_log      = (const float*)d_in[7];
  const float* D_skip     = (const float*)d_in[8];
  const float* init_st    = (const float*)d_in[9];
  const float* norm_w     = (const float*)d_in[10];
  const float* out_proj_w = (const float*)d_in[11];
  const float* mlp_w      = (const float*)d_in[12];
  const float* mlp_b      = (const float*)d_in[13];
  float* out = (float*)d_out;

  float* ws = (float*)d_ws;
  float* h    = ws; ws += (size_t)NT*HDIM;
  float* zx   = ws; ws += (size_t)EPROJ*NT;
  float* xbc  = ws; ws += (size_t)CDIM*NT;
  float* dt   = ws; ws += (size_t)NH*NT;
  float* acs  = ws; ws += (size_t)NH*NT;
  float* asum = ws; ws += (size_t)NB*NC*NH;
  float* S    = ws; ws += (size_t)NB*NC*NH*256;
  float* prev = ws; ws += (size_t)NB*NC*NH*256;
  float* y    = ws; ws += (size_t)NT*DIN;

  k_init_h<<<(NT*HDIM)/256, 256, 0, stream>>>(x, w_in, h);
  for(int i=0;i<NBLK;i++){
    k_inproj<<<NT/16, 256, 0, stream>>>(h, in_proj_w + i*EPROJ*HDIM, zx);
    k_conv  <<<CDIM*(NT/256), 256, 0, stream>>>(zx, conv_w + i*CDIM*KCONV, conv_b + i*CDIM, xbc);
    k_dt    <<<NH*(NT/256), 256, 0, stream>>>(zx, dt_bias + i*NH, dt);
    k_cumsum<<<NB*NC*NH, 64, 0, stream>>>(dt, A_log + i*NH, acs, asum);
    k_states<<<NB*NC*NH, 256, 0, stream>>>(xbc, dt, acs, asum, S);
    k_scan  <<<NB*NH*4, 64, 0, stream>>>(S, asum, init_st + i*NH*256, prev);
    k_y     <<<NB*NC*NH, 128, 0, stream>>>(xbc, zx, dt, acs, prev, D_skip + i*NH, y);
    k_out   <<<NT/32, 256, 0, stream>>>(y, norm_w + i*DIN, out_proj_w + i*HDIM*DIN,
                                        mlp_w + i*HDIM*HDIM, mlp_b + i*HDIM, h);
  }
  k_final<<<NT/256, 256, 0, stream>>>(h, w_out, out);
}

// Round 4
// 790.342 us; speedup vs baseline: 1.1139x; 1.1139x over previous
//
#include <hip/hip_runtime.h>
#include <math.h>

#define NB 4
#define SEQ 8192
#define NT (NB*SEQ)        // 32768 tokens
#define HDIM 64
#define NST 16
#define NBLK 4
#define KCONV 16
#define DIN 128
#define PDIM 16            // head dim
#define NH 8
#define CDIM 160
#define EPROJ 296
#define CH 128             // chunk length
#define NC 64              // chunks per sequence

__device__ __forceinline__ float sigf(float x){ return 1.0f/(1.0f+__expf(-x)); }

// h[t][d] = x[t] * w_in[d]
__global__ __launch_bounds__(256) void k_init_h(const float* __restrict__ x, const float* __restrict__ w_in,
                                                float* __restrict__ h){
  int i = blockIdx.x*256 + threadIdx.x;
  int t = i >> 6, d = i & 63;
  h[i] = x[t]*w_in[d];
}

// zx[e][t] = sum_d h[t][d] * w[e][d]   (channel-major output)
// lane = token (stores are 1 contiguous 256B segment/wave).
// Weights go down the SCALAR path: e is wave-uniform (readfirstlane) so
// w-row loads promote to s_load; FMAs read SGPR weights directly.
// grid = (NT/64, 2); wave w of block.y yhalf handles 37 e-rows (296 = 8*37).
__global__ __launch_bounds__(256) void k_inproj(const float* __restrict__ h, const float* __restrict__ w,
                                                float* __restrict__ zx){
  __shared__ __align__(16) float hl[64][68];
  int tid = threadIdx.x;
  int t0 = blockIdx.x * 64;
  const float4* hg = (const float4*)(h + (size_t)t0*HDIM);
#pragma unroll
  for(int k=0;k<4;k++){
    int fi = tid + k*256;            // 0..1023 float4s
    int tok = fi >> 4, c4 = fi & 15;
    *(float4*)&hl[tok][c4*4] = hg[fi];
  }
  __syncthreads();
  int lane = tid & 63;
  int wseg = __builtin_amdgcn_readfirstlane((int)(blockIdx.y*4 + (tid >> 6)));
  float4 hr[16];
#pragma unroll
  for(int i=0;i<16;i++) hr[i] = *(const float4*)&hl[lane][i*4];
  const float* wb = w + (size_t)wseg*37*HDIM;
  float* zb = zx + (size_t)t0 + lane + (size_t)wseg*37*NT;
#pragma unroll 2
  for(int j=0;j<37;j++){
    const float4* wr = (const float4*)(wb + (size_t)j*HDIM);
    float a0=0.f, a1=0.f, a2=0.f, a3=0.f;
#pragma unroll
    for(int i=0;i<4;i++){
      float4 w0 = wr[i*4+0], w1 = wr[i*4+1], w2 = wr[i*4+2], w3 = wr[i*4+3];
      a0 += hr[i*4+0].x*w0.x + hr[i*4+0].y*w0.y + hr[i*4+0].z*w0.z + hr[i*4+0].w*w0.w;
      a1 += hr[i*4+1].x*w1.x + hr[i*4+1].y*w1.y + hr[i*4+1].z*w1.z + hr[i*4+1].w*w1.w;
      a2 += hr[i*4+2].x*w2.x + hr[i*4+2].y*w2.y + hr[i*4+2].z*w2.z + hr[i*4+2].w*w2.w;
      a3 += hr[i*4+3].x*w3.x + hr[i*4+3].y*w3.y + hr[i*4+3].z*w3.z + hr[i*4+3].w*w3.w;
    }
    zb[(size_t)j*NT] = (a0+a1) + (a2+a3);
  }
}

// depthwise causal conv over l (16 taps) + bias + silu; input = zx channels [DIN, DIN+CDIM)
__global__ __launch_bounds__(256) void k_conv(const float* __restrict__ zx, const float* __restrict__ cw,
                                              const float* __restrict__ cb, float* __restrict__ xbc){
  int c = blockIdx.x >> 7;          // NT/256 = 128 tiles
  int t = (blockIdx.x & 127)*256 + threadIdx.x;
  int l = t & (SEQ-1);
  const float* in = zx + (size_t)(DIN + c)*NT;
  float acc = cb[c];
#pragma unroll
  for(int k=0;k<KCONV;k++){
    int ll = l - (KCONV-1) + k;
    float v = (ll >= 0) ? in[t - (KCONV-1) + k] : 0.f;
    acc += cw[c*KCONV + k] * v;
  }
  xbc[(size_t)c*NT + t] = acc * sigf(acc);
}

// dt[hh][t] = softplus(zx[288+hh][t] + dt_bias[hh])
__global__ __launch_bounds__(256) void k_dt(const float* __restrict__ zx, const float* __restrict__ dtb,
                                            float* __restrict__ dt){
  int hh = blockIdx.x >> 7;
  int t = (blockIdx.x & 127)*256 + threadIdx.x;
  float raw = zx[(size_t)(DIN + CDIM + hh)*NT + t] + dtb[hh];
  dt[(size_t)hh*NT + t] = (raw > 20.f) ? raw : log1pf(__expf(raw));
}

// per-(b,chunk,head): inclusive cumsum of dA = dt*A within chunk; store acs + chunk total asum
__global__ __launch_bounds__(64) void k_cumsum(const float* __restrict__ dt, const float* __restrict__ alog,
                                               float* __restrict__ acs, float* __restrict__ asum){
  int hh = blockIdx.x & 7;
  int c  = (blockIdx.x >> 3) & 63;
  int b  = blockIdx.x >> 9;
  int lane = threadIdx.x;
  int t0 = b*SEQ + c*CH;
  float A = -__expf(alog[hh]);
  float2 d2 = *(const float2*)(dt + (size_t)hh*NT + t0 + 2*lane);
  float v0 = d2.x*A, v1 = d2.y*A;
  float s = v0 + v1;
  for(int off=1; off<64; off<<=1){
    float o = __shfl_up(s, off);
    if(lane >= off) s += o;
  }
  float excl = s - (v0+v1);
  *(float2*)(acs + (size_t)hh*NT + t0 + 2*lane) = make_float2(excl+v0, excl+v0+v1);
  if(lane == 63) asum[(b*NC + c)*NH + hh] = s;
}

// chunk states S[b,c,h,p,n] = sum_s B[s,n] * xs[s,h,p] * dt[s] * exp(asum - acs[s])
__global__ __launch_bounds__(256) void k_states(const float* __restrict__ xbc, const float* __restrict__ dt,
                                                const float* __restrict__ acs, const float* __restrict__ asum,
                                                float* __restrict__ S){
  int hh = blockIdx.x & 7;
  int c  = (blockIdx.x >> 3) & 63;
  int b  = blockIdx.x >> 9;
  int t0 = b*SEQ + c*CH;
  __shared__ float Bl[CH][NST+4];
  __shared__ float Xl[CH][PDIM+4];
  __shared__ float Wl[CH];
  int tid = threadIdx.x;
#pragma unroll
  for(int r=0;r<8;r++){
    int idx = tid + r*256;
    int s = idx & 127, n = idx >> 7;
    Bl[s][n] = xbc[(size_t)(DIN + n)*NT + t0 + s];
    Xl[s][n] = xbc[(size_t)(hh*PDIM + n)*NT + t0 + s];
  }
  if(tid < 128){
    float as = asum[(b*NC + c)*NH + hh];
    Wl[tid] = dt[(size_t)hh*NT + t0 + tid] * __expf(as - acs[(size_t)hh*NT + t0 + tid]);
  }
  __syncthreads();
  int n = tid & 15, p = tid >> 4;
  float acc = 0.f;
#pragma unroll 4
  for(int s=0;s<CH;s++) acc += Bl[s][n] * (Xl[s][p] * Wl[s]);
  S[((size_t)(b*NC + c)*NH + hh)*256 + tid] = acc;
}

// sequential scan over 64 chunks: prev[c] = state entering chunk c
__global__ __launch_bounds__(64) void k_scan(const float* __restrict__ S, const float* __restrict__ asum,
                                             const float* __restrict__ init, float* __restrict__ prev){
  int q  = blockIdx.x & 3;
  int hh = (blockIdx.x >> 2) & 7;
  int b  = blockIdx.x >> 5;
  int el = q*64 + threadIdx.x;
  float r = init[hh*256 + el];
  float Sc = S[((size_t)(b*NC)*NH + hh)*256 + el];
  for(int c=0;c<NC;c++){
    size_t base = ((size_t)(b*NC + c)*NH + hh)*256 + el;
    float Sn = (c+1 < NC) ? S[base + NH*256] : 0.f;
    prev[base] = r;
    r = __expf(asum[(b*NC + c)*NH + hh])*r + Sc;
    Sc = Sn;
  }
}

// per-(b,chunk,head): Y = (tril(C B^T * decay * dt) X + C prev^T exp(acs) + D*xs) * silu(z)
__global__ __launch_bounds__(128) void k_y(const float* __restrict__ xbc, const float* __restrict__ zx,
                                           const float* __restrict__ dt, const float* __restrict__ acs,
                                           const float* __restrict__ prev, const float* __restrict__ dskip,
                                           float* __restrict__ y){
  int hh = blockIdx.x & 7;
  int c  = (blockIdx.x >> 3) & 63;
  int b  = blockIdx.x >> 9;
  int t0 = b*SEQ + c*CH;
  __shared__ __align__(16) float Bl[CH][NST+4];
  __shared__ __align__(16) float Xl[CH][PDIM+4];
  __shared__ float Al[CH];
  __shared__ float Dtl[CH];
  __shared__ float Pl[256];
  int tid = threadIdx.x;
#pragma unroll
  for(int r=0;r<16;r++){
    Bl[tid][r] = xbc[(size_t)(DIN + r)*NT + t0 + tid];
    Xl[tid][r] = xbc[(size_t)(hh*PDIM + r)*NT + t0 + tid];
  }
  Al[tid]  = acs[(size_t)hh*NT + t0 + tid];
  Dtl[tid] = dt[(size_t)hh*NT + t0 + tid];
  {
    size_t pb = ((size_t)(b*NC + c)*NH + hh)*256;
    Pl[tid]     = prev[pb + tid];
    Pl[tid+128] = prev[pb + tid + 128];
  }
  __syncthreads();
  int l = tid;
  float C[16];
#pragma unroll
  for(int n=0;n<16;n++) C[n] = xbc[(size_t)(DIN+NST+n)*NT + t0 + l];
  float a_l = Al[l];
  float acc[16];
#pragma unroll
  for(int p=0;p<16;p++) acc[p]=0.f;
  for(int s=0;s<=l;s++){
    const float4* bp = (const float4*)&Bl[s][0];
    float4 b0=bp[0], b1=bp[1], b2=bp[2], b3=bp[3];
    float dots = C[0]*b0.x + C[1]*b0.y + C[2]*b0.z + C[3]*b0.w
               + C[4]*b1.x + C[5]*b1.y + C[6]*b1.z + C[7]*b1.w
               + C[8]*b2.x + C[9]*b2.y + C[10]*b2.z + C[11]*b2.w
               + C[12]*b3.x + C[13]*b3.y + C[14]*b3.z + C[15]*b3.w;
    float w = dots * __expf(a_l - Al[s]) * Dtl[s];
    const float4* xp = (const float4*)&Xl[s][0];
    float4 x0=xp[0], x1=xp[1], x2=xp[2], x3=xp[3];
    acc[0] +=w*x0.x; acc[1] +=w*x0.y; acc[2] +=w*x0.z; acc[3] +=w*x0.w;
    acc[4] +=w*x1.x; acc[5] +=w*x1.y; acc[6] +=w*x1.z; acc[7] +=w*x1.w;
    acc[8] +=w*x2.x; acc[9] +=w*x2.y; acc[10]+=w*x2.z; acc[11]+=w*x2.w;
    acc[12]+=w*x3.x; acc[13]+=w*x3.y; acc[14]+=w*x3.z; acc[15]+=w*x3.w;
  }
  float ea = __expf(a_l);
#pragma unroll
  for(int p=0;p<16;p++){
    float ts = 0.f;
#pragma unroll
    for(int n=0;n<16;n++) ts += C[n]*Pl[p*16+n];
    acc[p] += ea*ts;
  }
  float Dk = dskip[hh];
#pragma unroll
  for(int p=0;p<16;p++){
    float zv = zx[(size_t)(hh*PDIM + p)*NT + t0 + l];
    float g = zv * sigf(zv);
    acc[p] = (acc[p] + Dk*Xl[l][p]) * g;
  }
  float4* yo = (float4*)(y + (size_t)(t0+l)*DIN + hh*PDIM);
  yo[0] = make_float4(acc[0], acc[1], acc[2], acc[3]);
  yo[1] = make_float4(acc[4], acc[5], acc[6], acc[7]);
  yo[2] = make_float4(acc[8], acc[9], acc[10],acc[11]);
  yo[3] = make_float4(acc[12],acc[13],acc[14],acc[15]);
}

// RMSNorm(y) -> out_proj(64x128) -> softsign -> mlp(64x64)+bias -> h +=
__global__ __launch_bounds__(256) void k_out(const float* __restrict__ y, const float* __restrict__ nw,
                                             const float* __restrict__ opw, const float* __restrict__ mw,
                                             const float* __restrict__ mb, float* __restrict__ h){
  __shared__ float ss[32];
  __shared__ float nwl[128];
  __shared__ float mbl[64];
  __shared__ __align__(16) float yt[32][132];
  __shared__ __align__(16) float W[64][132];
  int tid = threadIdx.x;
  int t0 = blockIdx.x * 32;
  int ln = tid & 63;

  if(tid < 128) nwl[tid] = nw[tid];
  else if(tid < 192) mbl[tid-128] = mb[tid-128];

  const float4* yg = (const float4*)(y + (size_t)t0*DIN);
#pragma unroll
  for(int k=0;k<4;k++){
    int fi = tid + k*256;
    float4 f = yg[fi];
    int tok = fi >> 5, c4 = fi & 31;
    *(float4*)&yt[tok][c4*4] = f;
    float d = f.x*f.x + f.y*f.y + f.z*f.z + f.w*f.w;
    d += __shfl_xor(d, 1); d += __shfl_xor(d, 2); d += __shfl_xor(d, 4);
    d += __shfl_xor(d, 8); d += __shfl_xor(d, 16);
    if((ln & 31) == 0) ss[tok] = d;
  }
  const float4* wg = (const float4*)opw;
#pragma unroll
  for(int k=0;k<8;k++){
    int fi = tid + k*256;
    int r = fi >> 5, c4 = fi & 31;
    *(float4*)&W[r][c4*4] = wg[fi];
  }
  __syncthreads();

#pragma unroll
  for(int k=0;k<4;k++){
    int fi = tid + k*256;
    int tok = fi >> 5, c4 = fi & 31;
    float r = rsqrtf(ss[tok]*(1.0f/128.0f) + 1e-5f);
    float4 v = *(float4*)&yt[tok][c4*4];
    float4 wv = ((const float4*)nwl)[c4];
    v.x *= r*wv.x; v.y *= r*wv.y; v.z *= r*wv.z; v.w *= r*wv.w;
    *(float4*)&yt[tok][c4*4] = v;
  }
  __syncthreads();

  int to = tid & 15, tk = tid >> 4;
  float acc0[4] = {0,0,0,0}, acc1[4] = {0,0,0,0};
#pragma unroll
  for(int n4=0;n4<32;n4++){
    float4 x0 = *(const float4*)&yt[2*tk][n4*4];
    float4 x1 = *(const float4*)&yt[2*tk+1][n4*4];
#pragma unroll
    for(int j=0;j<4;j++){
      float4 wv = *(const float4*)&W[to + 16*j][n4*4];
      acc0[j] += x0.x*wv.x + x0.y*wv.y + x0.z*wv.z + x0.w*wv.w;
      acc1[j] += x1.x*wv.x + x1.y*wv.y + x1.z*wv.z + x1.w*wv.w;
    }
  }
  __syncthreads();

  float* Wf = &W[0][0];
  float* tb = Wf + 4352;
#pragma unroll
  for(int j=0;j<4;j++){
    float o0 = acc0[j], o1 = acc1[j];
    tb[(2*tk)*68   + to + 16*j] = o0*rsqrtf(1.0f + o0*o0);
    tb[(2*tk+1)*68 + to + 16*j] = o1*rsqrtf(1.0f + o1*o1);
  }
  const float4* mg = (const float4*)mw;
#pragma unroll
  for(int k=0;k<4;k++){
    int fi = tid + k*256;
    int r = fi >> 4, c4 = fi & 15;
    *(float4*)&Wf[r*68 + c4*4] = mg[fi];
  }
  __syncthreads();

  float a20[4] = {0,0,0,0}, a21[4] = {0,0,0,0};
#pragma unroll
  for(int n4=0;n4<16;n4++){
    float4 x0 = *(const float4*)&tb[(2*tk)*68   + n4*4];
    float4 x1 = *(const float4*)&tb[(2*tk+1)*68 + n4*4];
#pragma unroll
    for(int j=0;j<4;j++){
      float4 wv = *(const float4*)&Wf[(to + 16*j)*68 + n4*4];
      a20[j] += x0.x*wv.x + x0.y*wv.y + x0.z*wv.z + x0.w*wv.w;
      a21[j] += x1.x*wv.x + x1.y*wv.y + x1.z*wv.z + x1.w*wv.w;
    }
  }
#pragma unroll
  for(int j=0;j<4;j++){
    int d = to + 16*j;
    float bias = mbl[d];
    h[(size_t)(t0 + 2*tk)*HDIM + d]     += a20[j] + bias;
    h[(size_t)(t0 + 2*tk + 1)*HDIM + d] += a21[j] + bias;
  }
}

__global__ __launch_bounds__(256) void k_final(const float* __restrict__ h, const float* __restrict__ wout,
                                               float* __restrict__ out){
  int t = blockIdx.x*256 + threadIdx.x;
  const float4* hp = (const float4*)(h + (size_t)t*HDIM);
  float acc = 0.f;
#pragma unroll
  for(int i=0;i<16;i++){
    float4 hv = hp[i]; float4 wv = ((const float4*)wout)[i];
    acc += hv.x*wv.x + hv.y*wv.y + hv.z*wv.z + hv.w*wv.w;
  }
  out[t] = acc;
}

extern "C" void kernel_launch(void* const* d_in, const int* in_sizes, int n_in,
                              void* d_out, int out_size, void* d_ws, size_t ws_size,
                              hipStream_t stream){
  const float* x          = (const float*)d_in[0];
  const float* w_in       = (const float*)d_in[1];
  const float* w_out      = (const float*)d_in[2];
  const float* in_proj_w  = (const float*)d_in[3];
  const float* conv_w     = (const float*)d_in[4];
  const float* conv_b     = (const float*)d_in[5];
  const float* dt_bias    = (const float*)d_in[6];
  const float* A_log      = (const float*)d_in[7];
  const float* D_skip     = (const float*)d_in[8];
  const float* init_st    = (const float*)d_in[9];
  const float* norm_w     = (const float*)d_in[10];
  const float* out_proj_w = (const float*)d_in[11];
  const float* mlp_w      = (const float*)d_in[12];
  const float* mlp_b      = (const float*)d_in[13];
  float* out = (float*)d_out;

  float* ws = (float*)d_ws;
  float* h    = ws; ws += (size_t)NT*HDIM;
  float* zx   = ws; ws += (size_t)EPROJ*NT;
  float* xbc  = ws; ws += (size_t)CDIM*NT;
  float* dt   = ws; ws += (size_t)NH*NT;
  float* acs  = ws; ws += (size_t)NH*NT;
  float* asum = ws; ws += (size_t)NB*NC*NH;
  float* S    = ws; ws += (size_t)NB*NC*NH*256;
  float* prev = ws; ws += (size_t)NB*NC*NH*256;
  float* y    = ws; ws += (size_t)NT*DIN;

  k_init_h<<<(NT*HDIM)/256, 256, 0, stream>>>(x, w_in, h);
  for(int i=0;i<NBLK;i++){
    dim3 gip(NT/64, 2);
    k_inproj<<<gip, 256, 0, stream>>>(h, in_proj_w + i*EPROJ*HDIM, zx);
    k_conv  <<<CDIM*(NT/256), 256, 0, stream>>>(zx, conv_w + i*CDIM*KCONV, conv_b + i*CDIM, xbc);
    k_dt    <<<NH*(NT/256), 256, 0, stream>>>(zx, dt_bias + i*NH, dt);
    k_cumsum<<<NB*NC*NH, 64, 0, stream>>>(dt, A_log + i*NH, acs, asum);
    k_states<<<NB*NC*NH, 256, 0, stream>>>(xbc, dt, acs, asum, S);
    k_scan  <<<NB*NH*4, 64, 0, stream>>>(S, asum, init_st + i*NH*256, prev);
    k_y     <<<NB*NC*NH, 128, 0, stream>>>(xbc, zx, dt, acs, prev, D_skip + i*NH, y);
    k_out   <<<NT/32, 256, 0, stream>>>(y, norm_w + i*DIN, out_proj_w + i*HDIM*DIN,
                                        mlp_w + i*HDIM*HDIM, mlp_b + i*HDIM, h);
  }
  k_final<<<NT/256, 256, 0, stream>>>(h, w_out, out);
}

// Round 5
// 758.197 us; speedup vs baseline: 1.1612x; 1.0424x over previous
//
#include <hip/hip_runtime.h>
#include <math.h>

#define NB 4
#define SEQ 8192
#define NT (NB*SEQ)        // 32768 tokens
#define HDIM 64
#define NST 16
#define NBLK 4
#define KCONV 16
#define DIN 128
#define PDIM 16            // head dim
#define NH 8
#define CDIM 160
#define EPROJ 296
#define CH 128             // chunk length
#define NC 64              // chunks per sequence

__device__ __forceinline__ float sigf(float x){ return 1.0f/(1.0f+__expf(-x)); }

// h[t][d] = x[t] * w_in[d]
__global__ __launch_bounds__(256) void k_init_h(const float* __restrict__ x, const float* __restrict__ w_in,
                                                float* __restrict__ h){
  int i = blockIdx.x*256 + threadIdx.x;
  int t = i >> 6, d = i & 63;
  h[i] = x[t]*w_in[d];
}

// zx[e][t] = sum_d h[t][d] * w[e][d]   (channel-major output)
// W half (148 rows, 37.9 KB) + 128-token h tile (34.8 KB) staged in LDS once
// per block (coalesced). Waves read weight rows via same-address broadcast
// ds_read_b128 (conflict-free); 2 tokens/lane so each weight fetch feeds
// 256 FMA-lanes. LDS 72.7 KB -> 2 blocks/CU.
__global__ __launch_bounds__(256) void k_inproj(const float* __restrict__ h, const float* __restrict__ w,
                                                float* __restrict__ zx){
  __shared__ __align__(16) float Wl[148*64];      // 37,888 B
  __shared__ __align__(16) float hl[128][68];     // 34,816 B
  int tid = threadIdx.x;
  int t0 = blockIdx.x * 128;
  int half = blockIdx.y;                          // 0 or 1
  // stage W half: 148*64 floats = 2368 float4
  const float4* wg = (const float4*)(w + (size_t)half*148*HDIM);
  float4* wl4 = (float4*)Wl;
#pragma unroll
  for(int k=0;k<10;k++){
    int fi = tid + k*256;
    if(fi < 2368) wl4[fi] = wg[fi];
  }
  // stage h tile: 128 tokens * 64 = 2048 float4
  const float4* hg = (const float4*)(h + (size_t)t0*HDIM);
#pragma unroll
  for(int k=0;k<8;k++){
    int fi = tid + k*256;
    int tok = fi >> 4, c4 = fi & 15;
    *(float4*)&hl[tok][c4*4] = hg[fi];
  }
  __syncthreads();
  int lane = tid & 63;
  int wv   = tid >> 6;        // 0..3
  float4 h0[16], h1[16];
#pragma unroll
  for(int i=0;i<16;i++){
    h0[i] = *(const float4*)&hl[lane][i*4];
    h1[i] = *(const float4*)&hl[64+lane][i*4];
  }
  int row0 = wv*37;
  float* zb = zx + (size_t)(half*148 + row0)*NT + t0 + lane;
  for(int j=0;j<37;j++){
    const float4* wr = (const float4*)&Wl[(size_t)(row0+j)*64];
    float a0=0.f, b0=0.f;
#pragma unroll
    for(int i=0;i<16;i++){
      float4 wq = wr[i];
      a0 += h0[i].x*wq.x + h0[i].y*wq.y + h0[i].z*wq.z + h0[i].w*wq.w;
      b0 += h1[i].x*wq.x + h1[i].y*wq.y + h1[i].z*wq.z + h1[i].w*wq.w;
    }
    zb[(size_t)j*NT]      = a0;
    zb[(size_t)j*NT + 64] = b0;
  }
}

// depthwise causal conv over l (16 taps) + bias + silu; input = zx channels [DIN, DIN+CDIM)
__global__ __launch_bounds__(256) void k_conv(const float* __restrict__ zx, const float* __restrict__ cw,
                                              const float* __restrict__ cb, float* __restrict__ xbc){
  int c = blockIdx.x >> 7;          // NT/256 = 128 tiles
  int t = (blockIdx.x & 127)*256 + threadIdx.x;
  int l = t & (SEQ-1);
  const float* in = zx + (size_t)(DIN + c)*NT;
  float acc = cb[c];
#pragma unroll
  for(int k=0;k<KCONV;k++){
    int ll = l - (KCONV-1) + k;
    float v = (ll >= 0) ? in[t - (KCONV-1) + k] : 0.f;
    acc += cw[c*KCONV + k] * v;
  }
  xbc[(size_t)c*NT + t] = acc * sigf(acc);
}

// dt[hh][t] = softplus(zx[288+hh][t] + dt_bias[hh])
__global__ __launch_bounds__(256) void k_dt(const float* __restrict__ zx, const float* __restrict__ dtb,
                                            float* __restrict__ dt){
  int hh = blockIdx.x >> 7;
  int t = (blockIdx.x & 127)*256 + threadIdx.x;
  float raw = zx[(size_t)(DIN + CDIM + hh)*NT + t] + dtb[hh];
  dt[(size_t)hh*NT + t] = (raw > 20.f) ? raw : log1pf(__expf(raw));
}

// per-(b,chunk,head): inclusive cumsum of dA = dt*A within chunk; store acs + chunk total asum
__global__ __launch_bounds__(64) void k_cumsum(const float* __restrict__ dt, const float* __restrict__ alog,
                                               float* __restrict__ acs, float* __restrict__ asum){
  int hh = blockIdx.x & 7;
  int c  = (blockIdx.x >> 3) & 63;
  int b  = blockIdx.x >> 9;
  int lane = threadIdx.x;
  int t0 = b*SEQ + c*CH;
  float A = -__expf(alog[hh]);
  float2 d2 = *(const float2*)(dt + (size_t)hh*NT + t0 + 2*lane);
  float v0 = d2.x*A, v1 = d2.y*A;
  float s = v0 + v1;
  for(int off=1; off<64; off<<=1){
    float o = __shfl_up(s, off);
    if(lane >= off) s += o;
  }
  float excl = s - (v0+v1);
  *(float2*)(acs + (size_t)hh*NT + t0 + 2*lane) = make_float2(excl+v0, excl+v0+v1);
  if(lane == 63) asum[(b*NC + c)*NH + hh] = s;
}

// chunk states S[b,c,h,p,n] = sum_s B[s,n] * xs[s,h,p] * dt[s] * exp(asum - acs[s])
__global__ __launch_bounds__(256) void k_states(const float* __restrict__ xbc, const float* __restrict__ dt,
                                                const float* __restrict__ acs, const float* __restrict__ asum,
                                                float* __restrict__ S){
  int hh = blockIdx.x & 7;
  int c  = (blockIdx.x >> 3) & 63;
  int b  = blockIdx.x >> 9;
  int t0 = b*SEQ + c*CH;
  __shared__ float Bl[CH][NST+4];
  __shared__ float Xl[CH][PDIM+4];
  __shared__ float Wl[CH];
  int tid = threadIdx.x;
#pragma unroll
  for(int r=0;r<8;r++){
    int idx = tid + r*256;
    int s = idx & 127, n = idx >> 7;
    Bl[s][n] = xbc[(size_t)(DIN + n)*NT + t0 + s];
    Xl[s][n] = xbc[(size_t)(hh*PDIM + n)*NT + t0 + s];
  }
  if(tid < 128){
    float as = asum[(b*NC + c)*NH + hh];
    Wl[tid] = dt[(size_t)hh*NT + t0 + tid] * __expf(as - acs[(size_t)hh*NT + t0 + tid]);
  }
  __syncthreads();
  int n = tid & 15, p = tid >> 4;
  float acc = 0.f;
#pragma unroll 4
  for(int s=0;s<CH;s++) acc += Bl[s][n] * (Xl[s][p] * Wl[s]);
  S[((size_t)(b*NC + c)*NH + hh)*256 + tid] = acc;
}

// sequential scan over 64 chunks: prev[c] = state entering chunk c
__global__ __launch_bounds__(64) void k_scan(const float* __restrict__ S, const float* __restrict__ asum,
                                             const float* __restrict__ init, float* __restrict__ prev){
  int q  = blockIdx.x & 3;
  int hh = (blockIdx.x >> 2) & 7;
  int b  = blockIdx.x >> 5;
  int el = q*64 + threadIdx.x;
  float r = init[hh*256 + el];
  float Sc = S[((size_t)(b*NC)*NH + hh)*256 + el];
  for(int c=0;c<NC;c++){
    size_t base = ((size_t)(b*NC + c)*NH + hh)*256 + el;
    float Sn = (c+1 < NC) ? S[base + NH*256] : 0.f;
    prev[base] = r;
    r = __expf(asum[(b*NC + c)*NH + hh])*r + Sc;
    Sc = Sn;
  }
}

// per-(b,chunk,head): Y = (tril(C B^T * decay * dt) X + C prev^T exp(acs) + D*xs) * silu(z)
__global__ __launch_bounds__(128) void k_y(const float* __restrict__ xbc, const float* __restrict__ zx,
                                           const float* __restrict__ dt, const float* __restrict__ acs,
                                           const float* __restrict__ prev, const float* __restrict__ dskip,
                                           float* __restrict__ y){
  int hh = blockIdx.x & 7;
  int c  = (blockIdx.x >> 3) & 63;
  int b  = blockIdx.x >> 9;
  int t0 = b*SEQ + c*CH;
  __shared__ __align__(16) float Bl[CH][NST+4];
  __shared__ __align__(16) float Xl[CH][PDIM+4];
  __shared__ float Al[CH];
  __shared__ float Dtl[CH];
  __shared__ float Pl[256];
  int tid = threadIdx.x;
#pragma unroll
  for(int r=0;r<16;r++){
    Bl[tid][r] = xbc[(size_t)(DIN + r)*NT + t0 + tid];
    Xl[tid][r] = xbc[(size_t)(hh*PDIM + r)*NT + t0 + tid];
  }
  Al[tid]  = acs[(size_t)hh*NT + t0 + tid];
  Dtl[tid] = dt[(size_t)hh*NT + t0 + tid];
  {
    size_t pb = ((size_t)(b*NC + c)*NH + hh)*256;
    Pl[tid]     = prev[pb + tid];
    Pl[tid+128] = prev[pb + tid + 128];
  }
  __syncthreads();
  int l = tid;
  float C[16];
#pragma unroll
  for(int n=0;n<16;n++) C[n] = xbc[(size_t)(DIN+NST+n)*NT + t0 + l];
  float a_l = Al[l];
  float acc[16];
#pragma unroll
  for(int p=0;p<16;p++) acc[p]=0.f;
  for(int s=0;s<=l;s++){
    const float4* bp = (const float4*)&Bl[s][0];
    float4 b0=bp[0], b1=bp[1], b2=bp[2], b3=bp[3];
    float dots = C[0]*b0.x + C[1]*b0.y + C[2]*b0.z + C[3]*b0.w
               + C[4]*b1.x + C[5]*b1.y + C[6]*b1.z + C[7]*b1.w
               + C[8]*b2.x + C[9]*b2.y + C[10]*b2.z + C[11]*b2.w
               + C[12]*b3.x + C[13]*b3.y + C[14]*b3.z + C[15]*b3.w;
    float w = dots * __expf(a_l - Al[s]) * Dtl[s];
    const float4* xp = (const float4*)&Xl[s][0];
    float4 x0=xp[0], x1=xp[1], x2=xp[2], x3=xp[3];
    acc[0] +=w*x0.x; acc[1] +=w*x0.y; acc[2] +=w*x0.z; acc[3] +=w*x0.w;
    acc[4] +=w*x1.x; acc[5] +=w*x1.y; acc[6] +=w*x1.z; acc[7] +=w*x1.w;
    acc[8] +=w*x2.x; acc[9] +=w*x2.y; acc[10]+=w*x2.z; acc[11]+=w*x2.w;
    acc[12]+=w*x3.x; acc[13]+=w*x3.y; acc[14]+=w*x3.z; acc[15]+=w*x3.w;
  }
  float ea = __expf(a_l);
#pragma unroll
  for(int p=0;p<16;p++){
    float ts = 0.f;
#pragma unroll
    for(int n=0;n<16;n++) ts += C[n]*Pl[p*16+n];
    acc[p] += ea*ts;
  }
  float Dk = dskip[hh];
#pragma unroll
  for(int p=0;p<16;p++){
    float zv = zx[(size_t)(hh*PDIM + p)*NT + t0 + l];
    float g = zv * sigf(zv);
    acc[p] = (acc[p] + Dk*Xl[l][p]) * g;
  }
  float4* yo = (float4*)(y + (size_t)(t0+l)*DIN + hh*PDIM);
  yo[0] = make_float4(acc[0], acc[1], acc[2], acc[3]);
  yo[1] = make_float4(acc[4], acc[5], acc[6], acc[7]);
  yo[2] = make_float4(acc[8], acc[9], acc[10],acc[11]);
  yo[3] = make_float4(acc[12],acc[13],acc[14],acc[15]);
}

// RMSNorm(y) -> out_proj(64x128) -> softsign -> mlp(64x64)+bias -> h +=
__global__ __launch_bounds__(256) void k_out(const float* __restrict__ y, const float* __restrict__ nw,
                                             const float* __restrict__ opw, const float* __restrict__ mw,
                                             const float* __restrict__ mb, float* __restrict__ h){
  __shared__ float ss[32];
  __shared__ float nwl[128];
  __shared__ float mbl[64];
  __shared__ __align__(16) float yt[32][132];
  __shared__ __align__(16) float W[64][132];
  int tid = threadIdx.x;
  int t0 = blockIdx.x * 32;
  int ln = tid & 63;

  if(tid < 128) nwl[tid] = nw[tid];
  else if(tid < 192) mbl[tid-128] = mb[tid-128];

  const float4* yg = (const float4*)(y + (size_t)t0*DIN);
#pragma unroll
  for(int k=0;k<4;k++){
    int fi = tid + k*256;
    float4 f = yg[fi];
    int tok = fi >> 5, c4 = fi & 31;
    *(float4*)&yt[tok][c4*4] = f;
    float d = f.x*f.x + f.y*f.y + f.z*f.z + f.w*f.w;
    d += __shfl_xor(d, 1); d += __shfl_xor(d, 2); d += __shfl_xor(d, 4);
    d += __shfl_xor(d, 8); d += __shfl_xor(d, 16);
    if((ln & 31) == 0) ss[tok] = d;
  }
  const float4* wg = (const float4*)opw;
#pragma unroll
  for(int k=0;k<8;k++){
    int fi = tid + k*256;
    int r = fi >> 5, c4 = fi & 31;
    *(float4*)&W[r][c4*4] = wg[fi];
  }
  __syncthreads();

#pragma unroll
  for(int k=0;k<4;k++){
    int fi = tid + k*256;
    int tok = fi >> 5, c4 = fi & 31;
    float r = rsqrtf(ss[tok]*(1.0f/128.0f) + 1e-5f);
    float4 v = *(float4*)&yt[tok][c4*4];
    float4 wv = ((const float4*)nwl)[c4];
    v.x *= r*wv.x; v.y *= r*wv.y; v.z *= r*wv.z; v.w *= r*wv.w;
    *(float4*)&yt[tok][c4*4] = v;
  }
  __syncthreads();

  int to = tid & 15, tk = tid >> 4;
  float acc0[4] = {0,0,0,0}, acc1[4] = {0,0,0,0};
#pragma unroll
  for(int n4=0;n4<32;n4++){
    float4 x0 = *(const float4*)&yt[2*tk][n4*4];
    float4 x1 = *(const float4*)&yt[2*tk+1][n4*4];
#pragma unroll
    for(int j=0;j<4;j++){
      float4 wv = *(const float4*)&W[to + 16*j][n4*4];
      acc0[j] += x0.x*wv.x + x0.y*wv.y + x0.z*wv.z + x0.w*wv.w;
      acc1[j] += x1.x*wv.x + x1.y*wv.y + x1.z*wv.z + x1.w*wv.w;
    }
  }
  __syncthreads();

  float* Wf = &W[0][0];
  float* tb = Wf + 4352;
#pragma unroll
  for(int j=0;j<4;j++){
    float o0 = acc0[j], o1 = acc1[j];
    tb[(2*tk)*68   + to + 16*j] = o0*rsqrtf(1.0f + o0*o0);
    tb[(2*tk+1)*68 + to + 16*j] = o1*rsqrtf(1.0f + o1*o1);
  }
  const float4* mg = (const float4*)mw;
#pragma unroll
  for(int k=0;k<4;k++){
    int fi = tid + k*256;
    int r = fi >> 4, c4 = fi & 15;
    *(float4*)&Wf[r*68 + c4*4] = mg[fi];
  }
  __syncthreads();

  float a20[4] = {0,0,0,0}, a21[4] = {0,0,0,0};
#pragma unroll
  for(int n4=0;n4<16;n4++){
    float4 x0 = *(const float4*)&tb[(2*tk)*68   + n4*4];
    float4 x1 = *(const float4*)&tb[(2*tk+1)*68 + n4*4];
#pragma unroll
    for(int j=0;j<4;j++){
      float4 wv = *(const float4*)&Wf[(to + 16*j)*68 + n4*4];
      a20[j] += x0.x*wv.x + x0.y*wv.y + x0.z*wv.z + x0.w*wv.w;
      a21[j] += x1.x*wv.x + x1.y*wv.y + x1.z*wv.z + x1.w*wv.w;
    }
  }
#pragma unroll
  for(int j=0;j<4;j++){
    int d = to + 16*j;
    float bias = mbl[d];
    h[(size_t)(t0 + 2*tk)*HDIM + d]     += a20[j] + bias;
    h[(size_t)(t0 + 2*tk + 1)*HDIM + d] += a21[j] + bias;
  }
}

__global__ __launch_bounds__(256) void k_final(const float* __restrict__ h, const float* __restrict__ wout,
                                               float* __restrict__ out){
  int t = blockIdx.x*256 + threadIdx.x;
  const float4* hp = (const float4*)(h + (size_t)t*HDIM);
  float acc = 0.f;
#pragma unroll
  for(int i=0;i<16;i++){
    float4 hv = hp[i]; float4 wv = ((const float4*)wout)[i];
    acc += hv.x*wv.x + hv.y*wv.y + hv.z*wv.z + hv.w*wv.w;
  }
  out[t] = acc;
}

extern "C" void kernel_launch(void* const* d_in, const int* in_sizes, int n_in,
                              void* d_out, int out_size, void* d_ws, size_t ws_size,
                              hipStream_t stream){
  const float* x          = (const float*)d_in[0];
  const float* w_in       = (const float*)d_in[1];
  const float* w_out      = (const float*)d_in[2];
  const float* in_proj_w  = (const float*)d_in[3];
  const float* conv_w     = (const float*)d_in[4];
  const float* conv_b     = (const float*)d_in[5];
  const float* dt_bias    = (const float*)d_in[6];
  const float* A_log      = (const float*)d_in[7];
  const float* D_skip     = (const float*)d_in[8];
  const float* init_st    = (const float*)d_in[9];
  const float* norm_w     = (const float*)d_in[10];
  const float* out_proj_w = (const float*)d_in[11];
  const float* mlp_w      = (const float*)d_in[12];
  const float* mlp_b      = (const float*)d_in[13];
  float* out = (float*)d_out;

  float* ws = (float*)d_ws;
  float* h    = ws; ws += (size_t)NT*HDIM;
  float* zx   = ws; ws += (size_t)EPROJ*NT;
  float* xbc  = ws; ws += (size_t)CDIM*NT;
  float* dt   = ws; ws += (size_t)NH*NT;
  float* acs  = ws; ws += (size_t)NH*NT;
  float* asum = ws; ws += (size_t)NB*NC*NH;
  float* S    = ws; ws += (size_t)NB*NC*NH*256;
  float* prev = ws; ws += (size_t)NB*NC*NH*256;
  float* y    = ws; ws += (size_t)NT*DIN;

  k_init_h<<<(NT*HDIM)/256, 256, 0, stream>>>(x, w_in, h);
  for(int i=0;i<NBLK;i++){
    dim3 gip(NT/128, 2);
    k_inproj<<<gip, 256, 0, stream>>>(h, in_proj_w + i*EPROJ*HDIM, zx);
    k_conv  <<<CDIM*(NT/256), 256, 0, stream>>>(zx, conv_w + i*CDIM*KCONV, conv_b + i*CDIM, xbc);
    k_dt    <<<NH*(NT/256), 256, 0, stream>>>(zx, dt_bias + i*NH, dt);
    k_cumsum<<<NB*NC*NH, 64, 0, stream>>>(dt, A_log + i*NH, acs, asum);
    k_states<<<NB*NC*NH, 256, 0, stream>>>(xbc, dt, acs, asum, S);
    k_scan  <<<NB*NH*4, 64, 0, stream>>>(S, asum, init_st + i*NH*256, prev);
    k_y     <<<NB*NC*NH, 128, 0, stream>>>(xbc, zx, dt, acs, prev, D_skip + i*NH, y);
    k_out   <<<NT/32, 256, 0, stream>>>(y, norm_w + i*DIN, out_proj_w + i*HDIM*DIN,
                                        mlp_w + i*HDIM*HDIM, mlp_b + i*HDIM, h);
  }
  k_final<<<NT/256, 256, 0, stream>>>(h, w_out, out);
}

// Round 6
// 649.221 us; speedup vs baseline: 1.3561x; 1.1679x over previous
//
#include <hip/hip_runtime.h>
#include <math.h>

#define NB 4
#define SEQ 8192
#define NT (NB*SEQ)        // 32768 tokens
#define HDIM 64
#define NST 16
#define NBLK 4
#define KCONV 16
#define DIN 128
#define PDIM 16            // head dim
#define NH 8
#define CDIM 160
#define EPROJ 296
#define CH 128             // chunk length
#define NC 64              // chunks per sequence

typedef __attribute__((ext_vector_type(8))) short short8;
typedef __attribute__((ext_vector_type(4))) float f32x4;

__device__ __forceinline__ float sigf(float x){ return 1.0f/(1.0f+__expf(-x)); }

__device__ __forceinline__ unsigned short bf16r(float f){
  unsigned int u = __float_as_uint(f);
  u = (u + 0x7fffu + ((u >> 16) & 1u)) >> 16;
  return (unsigned short)u;
}
__device__ __forceinline__ unsigned int pk_bf16(float a, float b){
  return (unsigned int)bf16r(a) | ((unsigned int)bf16r(b) << 16);
}
__device__ __forceinline__ float bf16f(unsigned short h){
  return __uint_as_float(((unsigned int)h) << 16);
}

// h[t][d] = x[t] * w_in[d]
__global__ __launch_bounds__(256) void k_init_h(const float* __restrict__ x, const float* __restrict__ w_in,
                                                float* __restrict__ h){
  int i = blockIdx.x*256 + threadIdx.x;
  int t = i >> 6, d = i & 63;
  h[i] = x[t]*w_in[d];
}

// zx[e][t] = sum_d h[t][d] * w[e][d]   (channel-major output)
__global__ __launch_bounds__(256) void k_inproj(const float* __restrict__ h, const float* __restrict__ w,
                                                float* __restrict__ zx){
  __shared__ __align__(16) float Wl[148*64];      // 37,888 B
  __shared__ __align__(16) float hl[128][68];     // 34,816 B
  int tid = threadIdx.x;
  int t0 = blockIdx.x * 128;
  int half = blockIdx.y;                          // 0 or 1
  const float4* wg = (const float4*)(w + (size_t)half*148*HDIM);
  float4* wl4 = (float4*)Wl;
#pragma unroll
  for(int k=0;k<10;k++){
    int fi = tid + k*256;
    if(fi < 2368) wl4[fi] = wg[fi];
  }
  const float4* hg = (const float4*)(h + (size_t)t0*HDIM);
#pragma unroll
  for(int k=0;k<8;k++){
    int fi = tid + k*256;
    int tok = fi >> 4, c4 = fi & 15;
    *(float4*)&hl[tok][c4*4] = hg[fi];
  }
  __syncthreads();
  int lane = tid & 63;
  int wv   = tid >> 6;        // 0..3
  float4 h0[16], h1[16];
#pragma unroll
  for(int i=0;i<16;i++){
    h0[i] = *(const float4*)&hl[lane][i*4];
    h1[i] = *(const float4*)&hl[64+lane][i*4];
  }
  int row0 = wv*37;
  float* zb = zx + (size_t)(half*148 + row0)*NT + t0 + lane;
  for(int j=0;j<37;j++){
    const float4* wr = (const float4*)&Wl[(size_t)(row0+j)*64];
    float a0=0.f, b0=0.f;
#pragma unroll
    for(int i=0;i<16;i++){
      float4 wq = wr[i];
      a0 += h0[i].x*wq.x + h0[i].y*wq.y + h0[i].z*wq.z + h0[i].w*wq.w;
      b0 += h1[i].x*wq.x + h1[i].y*wq.y + h1[i].z*wq.z + h1[i].w*wq.w;
    }
    zb[(size_t)j*NT]      = a0;
    zb[(size_t)j*NT + 64] = b0;
  }
}

// depthwise causal conv + bias + silu
__global__ __launch_bounds__(256) void k_conv(const float* __restrict__ zx, const float* __restrict__ cw,
                                              const float* __restrict__ cb, float* __restrict__ xbc){
  int c = blockIdx.x >> 7;
  int t = (blockIdx.x & 127)*256 + threadIdx.x;
  int l = t & (SEQ-1);
  const float* in = zx + (size_t)(DIN + c)*NT;
  float acc = cb[c];
#pragma unroll
  for(int k=0;k<KCONV;k++){
    int ll = l - (KCONV-1) + k;
    float v = (ll >= 0) ? in[t - (KCONV-1) + k] : 0.f;
    acc += cw[c*KCONV + k] * v;
  }
  xbc[(size_t)c*NT + t] = acc * sigf(acc);
}

// dt = softplus
__global__ __launch_bounds__(256) void k_dt(const float* __restrict__ zx, const float* __restrict__ dtb,
                                            float* __restrict__ dt){
  int hh = blockIdx.x >> 7;
  int t = (blockIdx.x & 127)*256 + threadIdx.x;
  float raw = zx[(size_t)(DIN + CDIM + hh)*NT + t] + dtb[hh];
  dt[(size_t)hh*NT + t] = (raw > 20.f) ? raw : log1pf(__expf(raw));
}

// per-chunk cumsum of dA
__global__ __launch_bounds__(64) void k_cumsum(const float* __restrict__ dt, const float* __restrict__ alog,
                                               float* __restrict__ acs, float* __restrict__ asum){
  int hh = blockIdx.x & 7;
  int c  = (blockIdx.x >> 3) & 63;
  int b  = blockIdx.x >> 9;
  int lane = threadIdx.x;
  int t0 = b*SEQ + c*CH;
  float A = -__expf(alog[hh]);
  float2 d2 = *(const float2*)(dt + (size_t)hh*NT + t0 + 2*lane);
  float v0 = d2.x*A, v1 = d2.y*A;
  float s = v0 + v1;
  for(int off=1; off<64; off<<=1){
    float o = __shfl_up(s, off);
    if(lane >= off) s += o;
  }
  float excl = s - (v0+v1);
  *(float2*)(acs + (size_t)hh*NT + t0 + 2*lane) = make_float2(excl+v0, excl+v0+v1);
  if(lane == 63) asum[(b*NC + c)*NH + hh] = s;
}

// chunk states
__global__ __launch_bounds__(256) void k_states(const float* __restrict__ xbc, const float* __restrict__ dt,
                                                const float* __restrict__ acs, const float* __restrict__ asum,
                                                float* __restrict__ S){
  int hh = blockIdx.x & 7;
  int c  = (blockIdx.x >> 3) & 63;
  int b  = blockIdx.x >> 9;
  int t0 = b*SEQ + c*CH;
  __shared__ float Bl[CH][NST+4];
  __shared__ float Xl[CH][PDIM+4];
  __shared__ float Wl[CH];
  int tid = threadIdx.x;
#pragma unroll
  for(int r=0;r<8;r++){
    int idx = tid + r*256;
    int s = idx & 127, n = idx >> 7;
    Bl[s][n] = xbc[(size_t)(DIN + n)*NT + t0 + s];
    Xl[s][n] = xbc[(size_t)(hh*PDIM + n)*NT + t0 + s];
  }
  if(tid < 128){
    float as = asum[(b*NC + c)*NH + hh];
    Wl[tid] = dt[(size_t)hh*NT + t0 + tid] * __expf(as - acs[(size_t)hh*NT + t0 + tid]);
  }
  __syncthreads();
  int n = tid & 15, p = tid >> 4;
  float acc = 0.f;
#pragma unroll 4
  for(int s=0;s<CH;s++) acc += Bl[s][n] * (Xl[s][p] * Wl[s]);
  S[((size_t)(b*NC + c)*NH + hh)*256 + tid] = acc;
}

// sequential inter-chunk scan
__global__ __launch_bounds__(64) void k_scan(const float* __restrict__ S, const float* __restrict__ asum,
                                             const float* __restrict__ init, float* __restrict__ prev){
  int q  = blockIdx.x & 3;
  int hh = (blockIdx.x >> 2) & 7;
  int b  = blockIdx.x >> 5;
  int el = q*64 + threadIdx.x;
  float r = init[hh*256 + el];
  float Sc = S[((size_t)(b*NC)*NH + hh)*256 + el];
  for(int c=0;c<NC;c++){
    size_t base = ((size_t)(b*NC + c)*NH + hh)*256 + el;
    float Sn = (c+1 < NC) ? S[base + NH*256] : 0.f;
    prev[base] = r;
    r = __expf(asum[(b*NC + c)*NH + hh])*r + Sc;
    Sc = Sn;
  }
}

// per-(b,chunk,head) MFMA SSD: S=C.B^T (16x16x32, K padded), decay/mask -> P(bf16),
// Y = P.[X*dt ; prev-ext] with K=160 (cols 128..143 = C*exp(acs) x prev^T fold-in).
__global__ __launch_bounds__(256) void k_y(const float* __restrict__ xbc, const float* __restrict__ zx,
                                           const float* __restrict__ dt, const float* __restrict__ acs,
                                           const float* __restrict__ prev, const float* __restrict__ dskip,
                                           float* __restrict__ y){
  __shared__ __align__(16) unsigned short P[128*168];   // 43008 B, row stride 168 bf16
  __shared__ __align__(16) unsigned short Cb[128*24];   // 6144 B, row stride 24 bf16 (48B)
  __shared__ __align__(16) unsigned short Bb[128*24];   // 6144 B
  __shared__ __align__(16) unsigned short XbT[16*168];  // 5376 B
  __shared__ __align__(16) float zl[16*132];            // 8448 B
  __shared__ float Al[128];
  __shared__ float Dtl[128];
  __shared__ __align__(16) unsigned short zbuf[16];     // 32 B zeros (K-pad source)

  int hh = blockIdx.x & 7;
  int c  = (blockIdx.x >> 3) & 63;
  int b  = blockIdx.x >> 9;
  int t0 = b*SEQ + c*CH;
  int tid = threadIdx.x;
  int lane = tid & 63, wid = tid >> 6;
  int quad = lane >> 4, lq = lane & 15;

  // ---- staging ----
  // B (16 ch) + C (16 ch) as bf16 pairs into Bb/Cb rows [s][n] (stride 24)
#pragma unroll
  for(int k=0;k<8;k++){
    int idx = tid + k*256;            // 0..2047
    int pr = idx >> 7;                // channel pair 0..15
    int s  = idx & 127;
    int ch = DIN + 2*pr;
    float f0 = xbc[(size_t)ch*NT + t0 + s];
    float f1 = xbc[(size_t)(ch+1)*NT + t0 + s];
    unsigned int pk = pk_bf16(f0, f1);
    unsigned short* dst = (pr < 8) ? &Bb[s*24 + 2*pr] : &Cb[s*24 + 2*(pr-8)];
    *(unsigned int*)dst = pk;
  }
  // XbT[p][s] = X[s][p]*dt[s] (bf16), rows stride 168
#pragma unroll
  for(int k=0;k<2;k++){
    int fi = tid + k*256;             // 0..511
    int p = fi >> 5, s4 = fi & 31;
    float4 xv = *(const float4*)&xbc[(size_t)(hh*PDIM + p)*NT + t0 + s4*4];
    float4 dv = *(const float4*)&dt[(size_t)hh*NT + t0 + s4*4];
    *(unsigned int*)&XbT[p*168 + s4*4]     = pk_bf16(xv.x*dv.x, xv.y*dv.y);
    *(unsigned int*)&XbT[p*168 + s4*4 + 2] = pk_bf16(xv.z*dv.z, xv.w*dv.w);
  }
  // prev ext: XbT[p][128+n] = prev[p][n]
  {
    size_t pb = ((size_t)(b*NC + c)*NH + hh)*256;
    int p = tid >> 4, n = tid & 15;
    XbT[p*168 + 128 + n] = bf16r(prev[pb + tid]);
  }
  // XbT pad cols 144..167 = 0
  if(tid < 192){
    int p = tid / 12, cc = tid - p*12;
    *(unsigned int*)&XbT[p*168 + 144 + 2*cc] = 0u;
  }
  // z tile [p][l]
#pragma unroll
  for(int k=0;k<2;k++){
    int fi = tid + k*256;
    int p = fi >> 5, s4 = fi & 31;
    *(float4*)&zl[p*132 + s4*4] = *(const float4*)&zx[(size_t)(hh*PDIM + p)*NT + t0 + s4*4];
  }
  if(tid < 128){
    Al[tid]  = acs[(size_t)hh*NT + t0 + tid];
    Dtl[tid] = dt[(size_t)hh*NT + t0 + tid];
  }
  if(tid < 16) zbuf[tid] = 0;
  // P pad cols 144..167 = 0 (24 bf16 = 3 x 8-short chunks)
  if(tid < 128){
    short8 z8 = {0,0,0,0,0,0,0,0};
    *(short8*)&P[tid*168 + 144] = z8;
    *(short8*)&P[tid*168 + 152] = z8;
    *(short8*)&P[tid*168 + 160] = z8;
  }
  __syncthreads();

  // ---- score phase: S = C.B^T, 32-row strip per wave ----
  int strip = wid*32;
  short8 afr[2];
  float al_r[2][4];
#pragma unroll
  for(int mt=0;mt<2;mt++){
    int row = strip + mt*16 + lq;
    const unsigned short* ap = (quad < 2) ? &Cb[row*24 + quad*8] : zbuf;
    afr[mt] = *(const short8*)ap;
#pragma unroll
    for(int r=0;r<4;r++) al_r[mt][r] = Al[strip + mt*16 + quad*4 + r];
  }
  for(int nt=0;nt<8;nt++){
    int rowb = nt*16 + lq;
    const unsigned short* bp = (quad < 2) ? &Bb[rowb*24 + quad*8] : zbuf;
    short8 bfr = *(const short8*)bp;
    float a_s = Al[nt*16 + lq];
    int scol = nt*16 + lq;
#pragma unroll
    for(int mt=0;mt<2;mt++){
      f32x4 acc = {0.f,0.f,0.f,0.f};
      acc = __builtin_amdgcn_mfma_f32_16x16x32_bf16(afr[mt], bfr, acc, 0, 0, 0);
      int lbase = strip + mt*16 + quad*4;
#pragma unroll
      for(int r=0;r<4;r++){
        int lrow = lbase + r;
        float e = __expf(al_r[mt][r] - a_s);
        float pv = acc[r]*e;
        pv = (scol <= lrow) ? pv : 0.f;
        P[lrow*168 + scol] = bf16r(pv);
      }
    }
  }
  // ext: P[l][128+n] = C[l][n]*exp(Al[l])
  {
    int row = tid >> 1, halfc = tid & 1;
    float ea = __expf(Al[row]);
    short8 cv = *(const short8*)&Cb[row*24 + halfc*8];
    unsigned short outv[8];
#pragma unroll
    for(int j=0;j<8;j++){
      float f = bf16f((unsigned short)cv[j]) * ea;
      outv[j] = bf16r(f);
    }
    short8 o8;
#pragma unroll
    for(int j=0;j<8;j++) o8[j] = (short)outv[j];
    *(short8*)&P[row*168 + 128 + halfc*8] = o8;
  }
  __syncthreads();

  // ---- PV phase: Y = P . XbT^T, K = 160 ----
  f32x4 acc2[2];
  acc2[0] = (f32x4){0.f,0.f,0.f,0.f};
  acc2[1] = (f32x4){0.f,0.f,0.f,0.f};
#pragma unroll
  for(int ks=0;ks<5;ks++){
    short8 bfr = *(const short8*)&XbT[lq*168 + ks*32 + quad*8];
#pragma unroll
    for(int mt=0;mt<2;mt++){
      short8 af = *(const short8*)&P[(strip + mt*16 + lq)*168 + ks*32 + quad*8];
      acc2[mt] = __builtin_amdgcn_mfma_f32_16x16x32_bf16(af, bfr, acc2[mt], 0, 0, 0);
    }
  }

  // ---- epilogue: +D*xraw, gate by silu(z), store ----
  float Dk = dskip[hh];
#pragma unroll
  for(int mt=0;mt<2;mt++){
#pragma unroll
    for(int r=0;r<4;r++){
      int l = strip + mt*16 + quad*4 + r;
      int p = lq;
      float zv = zl[p*132 + l];
      float g = zv * sigf(zv);
      float xdt = bf16f(XbT[p*168 + l]);
      float dtv = fmaxf(Dtl[l], 1e-30f);
      float xraw = xdt * __frcp_rn(dtv);
      float yv = (acc2[mt][r] + Dk*xraw) * g;
      y[(size_t)(t0+l)*DIN + hh*PDIM + p] = yv;
    }
  }
}

// RMSNorm(y) -> out_proj(64x128) -> softsign -> mlp(64x64)+bias -> h +=
__global__ __launch_bounds__(256) void k_out(const float* __restrict__ y, const float* __restrict__ nw,
                                             const float* __restrict__ opw, const float* __restrict__ mw,
                                             const float* __restrict__ mb, float* __restrict__ h){
  __shared__ float ss[32];
  __shared__ float nwl[128];
  __shared__ float mbl[64];
  __shared__ __align__(16) float yt[32][132];
  __shared__ __align__(16) float W[64][132];
  int tid = threadIdx.x;
  int t0 = blockIdx.x * 32;
  int ln = tid & 63;

  if(tid < 128) nwl[tid] = nw[tid];
  else if(tid < 192) mbl[tid-128] = mb[tid-128];

  const float4* yg = (const float4*)(y + (size_t)t0*DIN);
#pragma unroll
  for(int k=0;k<4;k++){
    int fi = tid + k*256;
    float4 f = yg[fi];
    int tok = fi >> 5, c4 = fi & 31;
    *(float4*)&yt[tok][c4*4] = f;
    float d = f.x*f.x + f.y*f.y + f.z*f.z + f.w*f.w;
    d += __shfl_xor(d, 1); d += __shfl_xor(d, 2); d += __shfl_xor(d, 4);
    d += __shfl_xor(d, 8); d += __shfl_xor(d, 16);
    if((ln & 31) == 0) ss[tok] = d;
  }
  const float4* wg = (const float4*)opw;
#pragma unroll
  for(int k=0;k<8;k++){
    int fi = tid + k*256;
    int r = fi >> 5, c4 = fi & 31;
    *(float4*)&W[r][c4*4] = wg[fi];
  }
  __syncthreads();

#pragma unroll
  for(int k=0;k<4;k++){
    int fi = tid + k*256;
    int tok = fi >> 5, c4 = fi & 31;
    float r = rsqrtf(ss[tok]*(1.0f/128.0f) + 1e-5f);
    float4 v = *(float4*)&yt[tok][c4*4];
    float4 wv = ((const float4*)nwl)[c4];
    v.x *= r*wv.x; v.y *= r*wv.y; v.z *= r*wv.z; v.w *= r*wv.w;
    *(float4*)&yt[tok][c4*4] = v;
  }
  __syncthreads();

  int to = tid & 15, tk = tid >> 4;
  float acc0[4] = {0,0,0,0}, acc1[4] = {0,0,0,0};
#pragma unroll
  for(int n4=0;n4<32;n4++){
    float4 x0 = *(const float4*)&yt[2*tk][n4*4];
    float4 x1 = *(const float4*)&yt[2*tk+1][n4*4];
#pragma unroll
    for(int j=0;j<4;j++){
      float4 wv = *(const float4*)&W[to + 16*j][n4*4];
      acc0[j] += x0.x*wv.x + x0.y*wv.y + x0.z*wv.z + x0.w*wv.w;
      acc1[j] += x1.x*wv.x + x1.y*wv.y + x1.z*wv.z + x1.w*wv.w;
    }
  }
  __syncthreads();

  float* Wf = &W[0][0];
  float* tb = Wf + 4352;
#pragma unroll
  for(int j=0;j<4;j++){
    float o0 = acc0[j], o1 = acc1[j];
    tb[(2*tk)*68   + to + 16*j] = o0*rsqrtf(1.0f + o0*o0);
    tb[(2*tk+1)*68 + to + 16*j] = o1*rsqrtf(1.0f + o1*o1);
  }
  const float4* mg = (const float4*)mw;
#pragma unroll
  for(int k=0;k<4;k++){
    int fi = tid + k*256;
    int r = fi >> 4, c4 = fi & 15;
    *(float4*)&Wf[r*68 + c4*4] = mg[fi];
  }
  __syncthreads();

  float a20[4] = {0,0,0,0}, a21[4] = {0,0,0,0};
#pragma unroll
  for(int n4=0;n4<16;n4++){
    float4 x0 = *(const float4*)&tb[(2*tk)*68   + n4*4];
    float4 x1 = *(const float4*)&tb[(2*tk+1)*68 + n4*4];
#pragma unroll
    for(int j=0;j<4;j++){
      float4 wv = *(const float4*)&Wf[(to + 16*j)*68 + n4*4];
      a20[j] += x0.x*wv.x + x0.y*wv.y + x0.z*wv.z + x0.w*wv.w;
      a21[j] += x1.x*wv.x + x1.y*wv.y + x1.z*wv.z + x1.w*wv.w;
    }
  }
#pragma unroll
  for(int j=0;j<4;j++){
    int d = to + 16*j;
    float bias = mbl[d];
    h[(size_t)(t0 + 2*tk)*HDIM + d]     += a20[j] + bias;
    h[(size_t)(t0 + 2*tk + 1)*HDIM + d] += a21[j] + bias;
  }
}

__global__ __launch_bounds__(256) void k_final(const float* __restrict__ h, const float* __restrict__ wout,
                                               float* __restrict__ out){
  int t = blockIdx.x*256 + threadIdx.x;
  const float4* hp = (const float4*)(h + (size_t)t*HDIM);
  float acc = 0.f;
#pragma unroll
  for(int i=0;i<16;i++){
    float4 hv = hp[i]; float4 wv = ((const float4*)wout)[i];
    acc += hv.x*wv.x + hv.y*wv.y + hv.z*wv.z + hv.w*wv.w;
  }
  out[t] = acc;
}

extern "C" void kernel_launch(void* const* d_in, const int* in_sizes, int n_in,
                              void* d_out, int out_size, void* d_ws, size_t ws_size,
                              hipStream_t stream){
  const float* x          = (const float*)d_in[0];
  const float* w_in       = (const float*)d_in[1];
  const float* w_out      = (const float*)d_in[2];
  const float* in_proj_w  = (const float*)d_in[3];
  const float* conv_w     = (const float*)d_in[4];
  const float* conv_b     = (const float*)d_in[5];
  const float* dt_bias    = (const float*)d_in[6];
  const float* A_log      = (const float*)d_in[7];
  const float* D_skip     = (const float*)d_in[8];
  const float* init_st    = (const float*)d_in[9];
  const float* norm_w     = (const float*)d_in[10];
  const float* out_proj_w = (const float*)d_in[11];
  const float* mlp_w      = (const float*)d_in[12];
  const float* mlp_b      = (const float*)d_in[13];
  float* out = (float*)d_out;

  float* ws = (float*)d_ws;
  float* h    = ws; ws += (size_t)NT*HDIM;
  float* zx   = ws; ws += (size_t)EPROJ*NT;
  float* xbc  = ws; ws += (size_t)CDIM*NT;
  float* dt   = ws; ws += (size_t)NH*NT;
  float* acs  = ws; ws += (size_t)NH*NT;
  float* asum = ws; ws += (size_t)NB*NC*NH;
  float* S    = ws; ws += (size_t)NB*NC*NH*256;
  float* prev = ws; ws += (size_t)NB*NC*NH*256;
  float* y    = ws; ws += (size_t)NT*DIN;

  k_init_h<<<(NT*HDIM)/256, 256, 0, stream>>>(x, w_in, h);
  for(int i=0;i<NBLK;i++){
    dim3 gip(NT/128, 2);
    k_inproj<<<gip, 256, 0, stream>>>(h, in_proj_w + i*EPROJ*HDIM, zx);
    k_conv  <<<CDIM*(NT/256), 256, 0, stream>>>(zx, conv_w + i*CDIM*KCONV, conv_b + i*CDIM, xbc);
    k_dt    <<<NH*(NT/256), 256, 0, stream>>>(zx, dt_bias + i*NH, dt);
    k_cumsum<<<NB*NC*NH, 64, 0, stream>>>(dt, A_log + i*NH, acs, asum);
    k_states<<<NB*NC*NH, 256, 0, stream>>>(xbc, dt, acs, asum, S);
    k_scan  <<<NB*NH*4, 64, 0, stream>>>(S, asum, init_st + i*NH*256, prev);
    k_y     <<<NB*NC*NH, 256, 0, stream>>>(xbc, zx, dt, acs, prev, D_skip + i*NH, y);
    k_out   <<<NT/32, 256, 0, stream>>>(y, norm_w + i*DIN, out_proj_w + i*HDIM*DIN,
                                        mlp_w + i*HDIM*HDIM, mlp_b + i*HDIM, h);
  }
  k_final<<<NT/256, 256, 0, stream>>>(h, w_out, out);
}

// Round 7
// 550.550 us; speedup vs baseline: 1.5991x; 1.1792x over previous
//
#include <hip/hip_runtime.h>
#include <math.h>

#define NB 4
#define SEQ 8192
#define NT (NB*SEQ)        // 32768 tokens
#define HDIM 64
#define NST 16
#define NBLK 4
#define KCONV 16
#define DIN 128
#define PDIM 16            // head dim
#define NH 8
#define CDIM 160
#define EPROJ 296
#define CH 128             // chunk length
#define NC 64              // chunks per sequence

typedef __attribute__((ext_vector_type(8))) short short8;
typedef __attribute__((ext_vector_type(4))) float f32x4;

__device__ __forceinline__ float sigf(float x){ return 1.0f/(1.0f+__expf(-x)); }

__device__ __forceinline__ unsigned short bf16r(float f){
  unsigned int u = __float_as_uint(f);
  u = (u + 0x7fffu + ((u >> 16) & 1u)) >> 16;
  return (unsigned short)u;
}
__device__ __forceinline__ unsigned int pk_bf16(float a, float b){
  return (unsigned int)bf16r(a) | ((unsigned int)bf16r(b) << 16);
}
__device__ __forceinline__ float bf16f(unsigned short h){
  return __uint_as_float(((unsigned int)h) << 16);
}

// h[t][d] = x[t] * w_in[d]
__global__ __launch_bounds__(256) void k_init_h(const float* __restrict__ x, const float* __restrict__ w_in,
                                                float* __restrict__ h){
  int i = blockIdx.x*256 + threadIdx.x;
  int t = i >> 6, d = i & 63;
  h[i] = x[t]*w_in[d];
}

// split all 4 layers' in_proj weights into bf16 hi/lo pair (once per call)
__global__ __launch_bounds__(256) void k_wsplit(const float* __restrict__ w,
                                                unsigned short* __restrict__ whi,
                                                unsigned short* __restrict__ wlo){
  int i = blockIdx.x*256 + threadIdx.x;
  if(i < NBLK*EPROJ*HDIM){
    float f = w[i];
    unsigned short hi = bf16r(f);
    float fh = bf16f(hi);
    whi[i] = hi;
    wlo[i] = bf16r(f - fh);
  }
}

// zx[e][t] = sum_d h[t][d]*w[e][d] via split-bf16 MFMA (hi*hi + hi*lo + lo*hi).
// A = W rows (m=e), B = tokens (n=t) -> C/D col = token => coalesced 64B stores.
// grid 512 blocks x 4 waves; wave: 16 tokens x all 296 e-rows (19 tiles, last masked).
__global__ __launch_bounds__(256) void k_inproj(const float* __restrict__ h,
                                                const unsigned short* __restrict__ whi,
                                                const unsigned short* __restrict__ wlo,
                                                float* __restrict__ zx){
  int tid = threadIdx.x;
  int lane = tid & 63, wid = tid >> 6;
  int quad = lane >> 4, lq = lane & 15;
  int t0 = blockIdx.x*64 + wid*16;

  // B-frags: h[t0+lq][kb*32 + quad*8 + j], split hi/lo
  const float* hp = h + (size_t)(t0+lq)*HDIM;
  short8 bh[2], bl[2];
#pragma unroll
  for(int kb=0;kb<2;kb++){
    float4 f0 = *(const float4*)(hp + kb*32 + quad*8);
    float4 f1 = *(const float4*)(hp + kb*32 + quad*8 + 4);
    float v[8] = {f0.x,f0.y,f0.z,f0.w,f1.x,f1.y,f1.z,f1.w};
#pragma unroll
    for(int j=0;j<8;j++){
      unsigned short hi = bf16r(v[j]);
      bh[kb][j] = (short)hi;
      bl[kb][j] = (short)bf16r(v[j] - bf16f(hi));
    }
  }

  for(int et=0; et<19; et++){
    int e_a = et*16 + lq;
    int ec = (e_a < EPROJ) ? e_a : (EPROJ-1);
    const unsigned short* wh = whi + (size_t)ec*HDIM + quad*8;
    const unsigned short* wl = wlo + (size_t)ec*HDIM + quad*8;
    short8 ah0 = *(const short8*)wh;
    short8 ah1 = *(const short8*)(wh + 32);
    short8 al0 = *(const short8*)wl;
    short8 al1 = *(const short8*)(wl + 32);
    f32x4 acc = {0.f,0.f,0.f,0.f};
    acc = __builtin_amdgcn_mfma_f32_16x16x32_bf16(ah0, bh[0], acc, 0, 0, 0);
    acc = __builtin_amdgcn_mfma_f32_16x16x32_bf16(ah1, bh[1], acc, 0, 0, 0);
    acc = __builtin_amdgcn_mfma_f32_16x16x32_bf16(ah0, bl[0], acc, 0, 0, 0);
    acc = __builtin_amdgcn_mfma_f32_16x16x32_bf16(ah1, bl[1], acc, 0, 0, 0);
    acc = __builtin_amdgcn_mfma_f32_16x16x32_bf16(al0, bh[0], acc, 0, 0, 0);
    acc = __builtin_amdgcn_mfma_f32_16x16x32_bf16(al1, bh[1], acc, 0, 0, 0);
#pragma unroll
    for(int r=0;r<4;r++){
      int e = et*16 + quad*4 + r;
      if(e < EPROJ) zx[(size_t)e*NT + t0 + lq] = acc[r];
    }
  }
}

// depthwise causal conv + bias + silu
__global__ __launch_bounds__(256) void k_conv(const float* __restrict__ zx, const float* __restrict__ cw,
                                              const float* __restrict__ cb, float* __restrict__ xbc){
  int c = blockIdx.x >> 7;
  int t = (blockIdx.x & 127)*256 + threadIdx.x;
  int l = t & (SEQ-1);
  const float* in = zx + (size_t)(DIN + c)*NT;
  float acc = cb[c];
#pragma unroll
  for(int k=0;k<KCONV;k++){
    int ll = l - (KCONV-1) + k;
    float v = (ll >= 0) ? in[t - (KCONV-1) + k] : 0.f;
    acc += cw[c*KCONV + k] * v;
  }
  xbc[(size_t)c*NT + t] = acc * sigf(acc);
}

// dt = softplus
__global__ __launch_bounds__(256) void k_dt(const float* __restrict__ zx, const float* __restrict__ dtb,
                                            float* __restrict__ dt){
  int hh = blockIdx.x >> 7;
  int t = (blockIdx.x & 127)*256 + threadIdx.x;
  float raw = zx[(size_t)(DIN + CDIM + hh)*NT + t] + dtb[hh];
  dt[(size_t)hh*NT + t] = (raw > 20.f) ? raw : log1pf(__expf(raw));
}

// per-chunk cumsum of dA
__global__ __launch_bounds__(64) void k_cumsum(const float* __restrict__ dt, const float* __restrict__ alog,
                                               float* __restrict__ acs, float* __restrict__ asum){
  int hh = blockIdx.x & 7;
  int c  = (blockIdx.x >> 3) & 63;
  int b  = blockIdx.x >> 9;
  int lane = threadIdx.x;
  int t0 = b*SEQ + c*CH;
  float A = -__expf(alog[hh]);
  float2 d2 = *(const float2*)(dt + (size_t)hh*NT + t0 + 2*lane);
  float v0 = d2.x*A, v1 = d2.y*A;
  float s = v0 + v1;
  for(int off=1; off<64; off<<=1){
    float o = __shfl_up(s, off);
    if(lane >= off) s += o;
  }
  float excl = s - (v0+v1);
  *(float2*)(acs + (size_t)hh*NT + t0 + 2*lane) = make_float2(excl+v0, excl+v0+v1);
  if(lane == 63) asum[(b*NC + c)*NH + hh] = s;
}

// chunk states
__global__ __launch_bounds__(256) void k_states(const float* __restrict__ xbc, const float* __restrict__ dt,
                                                const float* __restrict__ acs, const float* __restrict__ asum,
                                                float* __restrict__ S){
  int hh = blockIdx.x & 7;
  int c  = (blockIdx.x >> 3) & 63;
  int b  = blockIdx.x >> 9;
  int t0 = b*SEQ + c*CH;
  __shared__ float Bl[CH][NST+4];
  __shared__ float Xl[CH][PDIM+4];
  __shared__ float Wl[CH];
  int tid = threadIdx.x;
#pragma unroll
  for(int r=0;r<8;r++){
    int idx = tid + r*256;
    int s = idx & 127, n = idx >> 7;
    Bl[s][n] = xbc[(size_t)(DIN + n)*NT + t0 + s];
    Xl[s][n] = xbc[(size_t)(hh*PDIM + n)*NT + t0 + s];
  }
  if(tid < 128){
    float as = asum[(b*NC + c)*NH + hh];
    Wl[tid] = dt[(size_t)hh*NT + t0 + tid] * __expf(as - acs[(size_t)hh*NT + t0 + tid]);
  }
  __syncthreads();
  int n = tid & 15, p = tid >> 4;
  float acc = 0.f;
#pragma unroll 4
  for(int s=0;s<CH;s++) acc += Bl[s][n] * (Xl[s][p] * Wl[s]);
  S[((size_t)(b*NC + c)*NH + hh)*256 + tid] = acc;
}

// sequential inter-chunk scan
__global__ __launch_bounds__(64) void k_scan(const float* __restrict__ S, const float* __restrict__ asum,
                                             const float* __restrict__ init, float* __restrict__ prev){
  int q  = blockIdx.x & 3;
  int hh = (blockIdx.x >> 2) & 7;
  int b  = blockIdx.x >> 5;
  int el = q*64 + threadIdx.x;
  float r = init[hh*256 + el];
  float Sc = S[((size_t)(b*NC)*NH + hh)*256 + el];
  for(int c=0;c<NC;c++){
    size_t base = ((size_t)(b*NC + c)*NH + hh)*256 + el;
    float Sn = (c+1 < NC) ? S[base + NH*256] : 0.f;
    prev[base] = r;
    r = __expf(asum[(b*NC + c)*NH + hh])*r + Sc;
    Sc = Sn;
  }
}

// per-(b,chunk,head) MFMA SSD
__global__ __launch_bounds__(256) void k_y(const float* __restrict__ xbc, const float* __restrict__ zx,
                                           const float* __restrict__ dt, const float* __restrict__ acs,
                                           const float* __restrict__ prev, const float* __restrict__ dskip,
                                           float* __restrict__ y){
  __shared__ __align__(16) unsigned short P[128*168];
  __shared__ __align__(16) unsigned short Cb[128*24];
  __shared__ __align__(16) unsigned short Bb[128*24];
  __shared__ __align__(16) unsigned short XbT[16*168];
  __shared__ __align__(16) float zl[16*132];
  __shared__ float Al[128];
  __shared__ float Dtl[128];
  __shared__ __align__(16) unsigned short zbuf[16];

  int hh = blockIdx.x & 7;
  int c  = (blockIdx.x >> 3) & 63;
  int b  = blockIdx.x >> 9;
  int t0 = b*SEQ + c*CH;
  int tid = threadIdx.x;
  int lane = tid & 63, wid = tid >> 6;
  int quad = lane >> 4, lq = lane & 15;

#pragma unroll
  for(int k=0;k<8;k++){
    int idx = tid + k*256;
    int pr = idx >> 7;
    int s  = idx & 127;
    int ch = DIN + 2*pr;
    float f0 = xbc[(size_t)ch*NT + t0 + s];
    float f1 = xbc[(size_t)(ch+1)*NT + t0 + s];
    unsigned int pk = pk_bf16(f0, f1);
    unsigned short* dst = (pr < 8) ? &Bb[s*24 + 2*pr] : &Cb[s*24 + 2*(pr-8)];
    *(unsigned int*)dst = pk;
  }
#pragma unroll
  for(int k=0;k<2;k++){
    int fi = tid + k*256;
    int p = fi >> 5, s4 = fi & 31;
    float4 xv = *(const float4*)&xbc[(size_t)(hh*PDIM + p)*NT + t0 + s4*4];
    float4 dv = *(const float4*)&dt[(size_t)hh*NT + t0 + s4*4];
    *(unsigned int*)&XbT[p*168 + s4*4]     = pk_bf16(xv.x*dv.x, xv.y*dv.y);
    *(unsigned int*)&XbT[p*168 + s4*4 + 2] = pk_bf16(xv.z*dv.z, xv.w*dv.w);
  }
  {
    size_t pb = ((size_t)(b*NC + c)*NH + hh)*256;
    int p = tid >> 4, n = tid & 15;
    XbT[p*168 + 128 + n] = bf16r(prev[pb + tid]);
  }
  if(tid < 192){
    int p = tid / 12, cc = tid - p*12;
    *(unsigned int*)&XbT[p*168 + 144 + 2*cc] = 0u;
  }
#pragma unroll
  for(int k=0;k<2;k++){
    int fi = tid + k*256;
    int p = fi >> 5, s4 = fi & 31;
    *(float4*)&zl[p*132 + s4*4] = *(const float4*)&zx[(size_t)(hh*PDIM + p)*NT + t0 + s4*4];
  }
  if(tid < 128){
    Al[tid]  = acs[(size_t)hh*NT + t0 + tid];
    Dtl[tid] = dt[(size_t)hh*NT + t0 + tid];
  }
  if(tid < 16) zbuf[tid] = 0;
  if(tid < 128){
    short8 z8 = {0,0,0,0,0,0,0,0};
    *(short8*)&P[tid*168 + 144] = z8;
    *(short8*)&P[tid*168 + 152] = z8;
    *(short8*)&P[tid*168 + 160] = z8;
  }
  __syncthreads();

  int strip = wid*32;
  short8 afr[2];
  float al_r[2][4];
#pragma unroll
  for(int mt=0;mt<2;mt++){
    int row = strip + mt*16 + lq;
    const unsigned short* ap = (quad < 2) ? &Cb[row*24 + quad*8] : zbuf;
    afr[mt] = *(const short8*)ap;
#pragma unroll
    for(int r=0;r<4;r++) al_r[mt][r] = Al[strip + mt*16 + quad*4 + r];
  }
  for(int nt=0;nt<8;nt++){
    int rowb = nt*16 + lq;
    const unsigned short* bp = (quad < 2) ? &Bb[rowb*24 + quad*8] : zbuf;
    short8 bfr = *(const short8*)bp;
    float a_s = Al[nt*16 + lq];
    int scol = nt*16 + lq;
#pragma unroll
    for(int mt=0;mt<2;mt++){
      f32x4 acc = {0.f,0.f,0.f,0.f};
      acc = __builtin_amdgcn_mfma_f32_16x16x32_bf16(afr[mt], bfr, acc, 0, 0, 0);
      int lbase = strip + mt*16 + quad*4;
#pragma unroll
      for(int r=0;r<4;r++){
        int lrow = lbase + r;
        float e = __expf(al_r[mt][r] - a_s);
        float pv = acc[r]*e;
        pv = (scol <= lrow) ? pv : 0.f;
        P[lrow*168 + scol] = bf16r(pv);
      }
    }
  }
  {
    int row = tid >> 1, halfc = tid & 1;
    float ea = __expf(Al[row]);
    short8 cv = *(const short8*)&Cb[row*24 + halfc*8];
    short8 o8;
#pragma unroll
    for(int j=0;j<8;j++){
      float f = bf16f((unsigned short)cv[j]) * ea;
      o8[j] = (short)bf16r(f);
    }
    *(short8*)&P[row*168 + 128 + halfc*8] = o8;
  }
  __syncthreads();

  f32x4 acc2[2];
  acc2[0] = (f32x4){0.f,0.f,0.f,0.f};
  acc2[1] = (f32x4){0.f,0.f,0.f,0.f};
#pragma unroll
  for(int ks=0;ks<5;ks++){
    short8 bfr = *(const short8*)&XbT[lq*168 + ks*32 + quad*8];
#pragma unroll
    for(int mt=0;mt<2;mt++){
      short8 af = *(const short8*)&P[(strip + mt*16 + lq)*168 + ks*32 + quad*8];
      acc2[mt] = __builtin_amdgcn_mfma_f32_16x16x32_bf16(af, bfr, acc2[mt], 0, 0, 0);
    }
  }

  float Dk = dskip[hh];
#pragma unroll
  for(int mt=0;mt<2;mt++){
#pragma unroll
    for(int r=0;r<4;r++){
      int l = strip + mt*16 + quad*4 + r;
      int p = lq;
      float zv = zl[p*132 + l];
      float g = zv * sigf(zv);
      float xdt = bf16f(XbT[p*168 + l]);
      float dtv = fmaxf(Dtl[l], 1e-30f);
      float xraw = xdt * __frcp_rn(dtv);
      float yv = (acc2[mt][r] + Dk*xraw) * g;
      y[(size_t)(t0+l)*DIN + hh*PDIM + p] = yv;
    }
  }
}

// RMSNorm(y) -> out_proj(64x128) -> softsign -> mlp(64x64)+bias -> h +=
__global__ __launch_bounds__(256) void k_out(const float* __restrict__ y, const float* __restrict__ nw,
                                             const float* __restrict__ opw, const float* __restrict__ mw,
                                             const float* __restrict__ mb, float* __restrict__ h){
  __shared__ float ss[32];
  __shared__ float nwl[128];
  __shared__ float mbl[64];
  __shared__ __align__(16) float yt[32][132];
  __shared__ __align__(16) float W[64][132];
  int tid = threadIdx.x;
  int t0 = blockIdx.x * 32;
  int ln = tid & 63;

  if(tid < 128) nwl[tid] = nw[tid];
  else if(tid < 192) mbl[tid-128] = mb[tid-128];

  const float4* yg = (const float4*)(y + (size_t)t0*DIN);
#pragma unroll
  for(int k=0;k<4;k++){
    int fi = tid + k*256;
    float4 f = yg[fi];
    int tok = fi >> 5, c4 = fi & 31;
    *(float4*)&yt[tok][c4*4] = f;
    float d = f.x*f.x + f.y*f.y + f.z*f.z + f.w*f.w;
    d += __shfl_xor(d, 1); d += __shfl_xor(d, 2); d += __shfl_xor(d, 4);
    d += __shfl_xor(d, 8); d += __shfl_xor(d, 16);
    if((ln & 31) == 0) ss[tok] = d;
  }
  const float4* wg = (const float4*)opw;
#pragma unroll
  for(int k=0;k<8;k++){
    int fi = tid + k*256;
    int r = fi >> 5, c4 = fi & 31;
    *(float4*)&W[r][c4*4] = wg[fi];
  }
  __syncthreads();

#pragma unroll
  for(int k=0;k<4;k++){
    int fi = tid + k*256;
    int tok = fi >> 5, c4 = fi & 31;
    float r = rsqrtf(ss[tok]*(1.0f/128.0f) + 1e-5f);
    float4 v = *(float4*)&yt[tok][c4*4];
    float4 wv = ((const float4*)nwl)[c4];
    v.x *= r*wv.x; v.y *= r*wv.y; v.z *= r*wv.z; v.w *= r*wv.w;
    *(float4*)&yt[tok][c4*4] = v;
  }
  __syncthreads();

  int to = tid & 15, tk = tid >> 4;
  float acc0[4] = {0,0,0,0}, acc1[4] = {0,0,0,0};
#pragma unroll
  for(int n4=0;n4<32;n4++){
    float4 x0 = *(const float4*)&yt[2*tk][n4*4];
    float4 x1 = *(const float4*)&yt[2*tk+1][n4*4];
#pragma unroll
    for(int j=0;j<4;j++){
      float4 wv = *(const float4*)&W[to + 16*j][n4*4];
      acc0[j] += x0.x*wv.x + x0.y*wv.y + x0.z*wv.z + x0.w*wv.w;
      acc1[j] += x1.x*wv.x + x1.y*wv.y + x1.z*wv.z + x1.w*wv.w;
    }
  }
  __syncthreads();

  float* Wf = &W[0][0];
  float* tb = Wf + 4352;
#pragma unroll
  for(int j=0;j<4;j++){
    float o0 = acc0[j], o1 = acc1[j];
    tb[(2*tk)*68   + to + 16*j] = o0*rsqrtf(1.0f + o0*o0);
    tb[(2*tk+1)*68 + to + 16*j] = o1*rsqrtf(1.0f + o1*o1);
  }
  const float4* mg = (const float4*)mw;
#pragma unroll
  for(int k=0;k<4;k++){
    int fi = tid + k*256;
    int r = fi >> 4, c4 = fi & 15;
    *(float4*)&Wf[r*68 + c4*4] = mg[fi];
  }
  __syncthreads();

  float a20[4] = {0,0,0,0}, a21[4] = {0,0,0,0};
#pragma unroll
  for(int n4=0;n4<16;n4++){
    float4 x0 = *(const float4*)&tb[(2*tk)*68   + n4*4];
    float4 x1 = *(const float4*)&tb[(2*tk+1)*68 + n4*4];
#pragma unroll
    for(int j=0;j<4;j++){
      float4 wv = *(const float4*)&Wf[(to + 16*j)*68 + n4*4];
      a20[j] += x0.x*wv.x + x0.y*wv.y + x0.z*wv.z + x0.w*wv.w;
      a21[j] += x1.x*wv.x + x1.y*wv.y + x1.z*wv.z + x1.w*wv.w;
    }
  }
#pragma unroll
  for(int j=0;j<4;j++){
    int d = to + 16*j;
    float bias = mbl[d];
    h[(size_t)(t0 + 2*tk)*HDIM + d]     += a20[j] + bias;
    h[(size_t)(t0 + 2*tk + 1)*HDIM + d] += a21[j] + bias;
  }
}

__global__ __launch_bounds__(256) void k_final(const float* __restrict__ h, const float* __restrict__ wout,
                                               float* __restrict__ out){
  int t = blockIdx.x*256 + threadIdx.x;
  const float4* hp = (const float4*)(h + (size_t)t*HDIM);
  float acc = 0.f;
#pragma unroll
  for(int i=0;i<16;i++){
    float4 hv = hp[i]; float4 wv = ((const float4*)wout)[i];
    acc += hv.x*wv.x + hv.y*wv.y + hv.z*wv.z + hv.w*wv.w;
  }
  out[t] = acc;
}

extern "C" void kernel_launch(void* const* d_in, const int* in_sizes, int n_in,
                              void* d_out, int out_size, void* d_ws, size_t ws_size,
                              hipStream_t stream){
  const float* x          = (const float*)d_in[0];
  const float* w_in       = (const float*)d_in[1];
  const float* w_out      = (const float*)d_in[2];
  const float* in_proj_w  = (const float*)d_in[3];
  const float* conv_w     = (const float*)d_in[4];
  const float* conv_b     = (const float*)d_in[5];
  const float* dt_bias    = (const float*)d_in[6];
  const float* A_log      = (const float*)d_in[7];
  const float* D_skip     = (const float*)d_in[8];
  const float* init_st    = (const float*)d_in[9];
  const float* norm_w     = (const float*)d_in[10];
  const float* out_proj_w = (const float*)d_in[11];
  const float* mlp_w      = (const float*)d_in[12];
  const float* mlp_b      = (const float*)d_in[13];
  float* out = (float*)d_out;

  float* ws = (float*)d_ws;
  float* h    = ws; ws += (size_t)NT*HDIM;
  float* zx   = ws; ws += (size_t)EPROJ*NT;
  float* xbc  = ws; ws += (size_t)CDIM*NT;
  float* dt   = ws; ws += (size_t)NH*NT;
  float* acs  = ws; ws += (size_t)NH*NT;
  float* asum = ws; ws += (size_t)NB*NC*NH;
  float* S    = ws; ws += (size_t)NB*NC*NH*256;
  float* prev = ws; ws += (size_t)NB*NC*NH*256;
  float* y    = ws; ws += (size_t)NT*DIN;
  unsigned short* whi = (unsigned short*)ws; ws += (size_t)(NBLK*EPROJ*HDIM)/2;
  unsigned short* wlo = (unsigned short*)ws; ws += (size_t)(NBLK*EPROJ*HDIM)/2;

  k_init_h<<<(NT*HDIM)/256, 256, 0, stream>>>(x, w_in, h);
  k_wsplit<<<(NBLK*EPROJ*HDIM + 255)/256, 256, 0, stream>>>(in_proj_w, whi, wlo);
  for(int i=0;i<NBLK;i++){
    k_inproj<<<NT/64, 256, 0, stream>>>(h, whi + (size_t)i*EPROJ*HDIM,
                                        wlo + (size_t)i*EPROJ*HDIM, zx);
    k_conv  <<<CDIM*(NT/256), 256, 0, stream>>>(zx, conv_w + i*CDIM*KCONV, conv_b + i*CDIM, xbc);
    k_dt    <<<NH*(NT/256), 256, 0, stream>>>(zx, dt_bias + i*NH, dt);
    k_cumsum<<<NB*NC*NH, 64, 0, stream>>>(dt, A_log + i*NH, acs, asum);
    k_states<<<NB*NC*NH, 256, 0, stream>>>(xbc, dt, acs, asum, S);
    k_scan  <<<NB*NH*4, 64, 0, stream>>>(S, asum, init_st + i*NH*256, prev);
    k_y     <<<NB*NC*NH, 256, 0, stream>>>(xbc, zx, dt, acs, prev, D_skip + i*NH, y);
    k_out   <<<NT/32, 256, 0, stream>>>(y, norm_w + i*DIN, out_proj_w + i*HDIM*DIN,
                                        mlp_w + i*HDIM*HDIM, mlp_b + i*HDIM, h);
  }
  k_final<<<NT/256, 256, 0, stream>>>(h, w_out, out);
}